// Round 1
// baseline (7794.073 us; speedup 1.0000x reference)
//
#include <hip/hip_runtime.h>
#include <math.h>

#define D_MODEL 1024
#define NHEADS 16
#define HEAD_DIM 64
#define SEQ 2048
#define BATCH 2
#define TOK (BATCH*SEQ)     // 4096 tokens
#define MLP_DIM 4096

#define F_BIAS  1
#define F_GELU  2
#define F_RESID 4

// ---------------- LayerNorm (one block per row, 256 thr, 4 floats/thr) ----------------
__global__ __launch_bounds__(256)
void ln_kernel(const float* __restrict__ x, const float* __restrict__ w,
               const float* __restrict__ b, float* __restrict__ out)
{
    const int row = blockIdx.x;
    const int t = threadIdx.x;
    const float* xr = x + (size_t)row * D_MODEL;
    float4 v = *(const float4*)(xr + t * 4);
    float s  = v.x + v.y + v.z + v.w;
    float ss = v.x*v.x + v.y*v.y + v.z*v.z + v.w*v.w;
    #pragma unroll
    for (int off = 32; off > 0; off >>= 1) {
        s  += __shfl_down(s, off);
        ss += __shfl_down(ss, off);
    }
    __shared__ float red[8];
    const int wid = t >> 6, lane = t & 63;
    if (lane == 0) { red[wid] = s; red[4 + wid] = ss; }
    __syncthreads();
    const float st  = red[0] + red[1] + red[2] + red[3];
    const float sst = red[4] + red[5] + red[6] + red[7];
    const float mu  = st * (1.0f / D_MODEL);
    const float var = sst * (1.0f / D_MODEL) - mu * mu;
    const float rs  = rsqrtf(var + 1e-5f);
    const float4 wv = *(const float4*)(w + t * 4);
    const float4 bv = *(const float4*)(b + t * 4);
    float4 o;
    o.x = (v.x - mu) * rs * wv.x + bv.x;
    o.y = (v.y - mu) * rs * wv.y + bv.y;
    o.z = (v.z - mu) * rs * wv.z + bv.z;
    o.w = (v.w - mu) * rs * wv.w + bv.w;
    *(float4*)(out + (size_t)row * D_MODEL + t * 4) = o;
}

// ---------------- SGEMM: C[M,N] = A[M,K] @ W[K,N] (+bias)(+gelu)(+resid-inplace) ----
// 128x128 tile, BK=16, 256 threads, 8x8 microtile per thread.
// All dims divisible: M=4096, N in {1024,3072,4096}, K in {1024,4096}.
template<int FLAGS>
__global__ __launch_bounds__(256)
void sgemm_kernel(const float* __restrict__ A, int lda,
                  const float* __restrict__ W, int ldw,
                  const float* __restrict__ bias,
                  float* __restrict__ C, int ldc,
                  int K)
{
    __shared__ float As[16][128];   // As[k][m]
    __shared__ float Bs[16][128];   // Bs[k][n]
    const int tid = threadIdx.x;
    const int tm = tid >> 4;        // 0..15
    const int tn = tid & 15;        // 0..15
    const int bm = blockIdx.y, bn = blockIdx.x;

    float acc[8][8] = {};

    const int ar = tid >> 2;            // 0..63 (A tile row, +64 second half)
    const int ac = (tid & 3) << 2;      // 0,4,8,12 (A tile col, float4)
    const int br = tid >> 5;            // 0..7 (B tile row, +8 second half)
    const int bc = (tid & 31) << 2;     // 0..124 (B tile col, float4)

    const float* Aq = A + (size_t)(bm * 128 + ar) * lda + ac;
    const float* Wq = W + (size_t)br * ldw + bn * 128 + bc;

    for (int k0 = 0; k0 < K; k0 += 16) {
        float4 a0 = *(const float4*)(Aq + k0);
        float4 a1 = *(const float4*)(Aq + (size_t)64 * lda + k0);
        float4 b0 = *(const float4*)(Wq + (size_t)k0 * ldw);
        float4 b1 = *(const float4*)(Wq + (size_t)(k0 + 8) * ldw);
        __syncthreads();   // previous-iter LDS reads done before overwrite
        As[ac + 0][ar] = a0.x; As[ac + 1][ar] = a0.y;
        As[ac + 2][ar] = a0.z; As[ac + 3][ar] = a0.w;
        As[ac + 0][ar + 64] = a1.x; As[ac + 1][ar + 64] = a1.y;
        As[ac + 2][ar + 64] = a1.z; As[ac + 3][ar + 64] = a1.w;
        *(float4*)&Bs[br][bc]     = b0;
        *(float4*)&Bs[br + 8][bc] = b1;
        __syncthreads();
        #pragma unroll
        for (int k = 0; k < 16; ++k) {
            float4 a0v = *(float4*)&As[k][tm * 8];
            float4 a1v = *(float4*)&As[k][tm * 8 + 4];
            float4 b0v = *(float4*)&Bs[k][tn * 8];
            float4 b1v = *(float4*)&Bs[k][tn * 8 + 4];
            float av[8] = {a0v.x, a0v.y, a0v.z, a0v.w, a1v.x, a1v.y, a1v.z, a1v.w};
            float bv[8] = {b0v.x, b0v.y, b0v.z, b0v.w, b1v.x, b1v.y, b1v.z, b1v.w};
            #pragma unroll
            for (int i = 0; i < 8; ++i)
                #pragma unroll
                for (int j = 0; j < 8; ++j)
                    acc[i][j] = fmaf(av[i], bv[j], acc[i][j]);
        }
    }

    const int row0 = bm * 128 + tm * 8;
    const int col0 = bn * 128 + tn * 8;
    #pragma unroll
    for (int i = 0; i < 8; ++i) {
        #pragma unroll
        for (int j = 0; j < 8; ++j) {
            float v = acc[i][j];
            if (FLAGS & F_BIAS)  v += bias[col0 + j];
            if (FLAGS & F_GELU)  v = 0.5f * v * (1.0f + erff(v * 0.70710678118654752f));
            if (FLAGS & F_RESID) v += C[(size_t)(row0 + i) * ldc + col0 + j];
            C[(size_t)(row0 + i) * ldc + col0 + j] = v;
        }
    }
}

// ---------------- Attention: one thread owns one q-row; online softmax ----------------
// grid (S/256, B*H); K/V tiles (32 kv rows x 64) staged in LDS, broadcast reads.
__global__ __launch_bounds__(256)
void attn_kernel(const float* __restrict__ qp, const float* __restrict__ kp,
                 const float* __restrict__ vp, float* __restrict__ o)
{
    const int bh = blockIdx.y;
    const int b = bh >> 4;
    const int h = bh & 15;
    const int q = blockIdx.x * 256 + threadIdx.x;
    const size_t base = ((size_t)b * SEQ) * D_MODEL + (size_t)h * HEAD_DIM;
    const float* qrow = qp + base + (size_t)q * D_MODEL;
    const float* Kb = kp + base;
    const float* Vb = vp + base;

    float qv[64];
    #pragma unroll
    for (int d = 0; d < 64; d += 4) {
        float4 t = *(const float4*)(qrow + d);
        qv[d] = t.x; qv[d + 1] = t.y; qv[d + 2] = t.z; qv[d + 3] = t.w;
    }
    float m_run = -1e30f, l_run = 0.0f;
    float acc[64];
    #pragma unroll
    for (int d = 0; d < 64; ++d) acc[d] = 0.0f;

    __shared__ float Kl[32][64];
    __shared__ float Vl[32][64];
    const int lr = threadIdx.x >> 3;        // 0..31
    const int lc = (threadIdx.x & 7) << 3;  // 0..56

    for (int t0 = 0; t0 < SEQ; t0 += 32) {
        __syncthreads();   // everyone done with previous tile
        const float* Ksrc = Kb + (size_t)(t0 + lr) * D_MODEL + lc;
        const float* Vsrc = Vb + (size_t)(t0 + lr) * D_MODEL + lc;
        *(float4*)&Kl[lr][lc]     = *(const float4*)(Ksrc);
        *(float4*)&Kl[lr][lc + 4] = *(const float4*)(Ksrc + 4);
        *(float4*)&Vl[lr][lc]     = *(const float4*)(Vsrc);
        *(float4*)&Vl[lr][lc + 4] = *(const float4*)(Vsrc + 4);
        __syncthreads();

        float s[32];
        float tmax = -1e30f;
        #pragma unroll
        for (int j = 0; j < 32; ++j) {
            float acs = 0.0f;
            #pragma unroll
            for (int d = 0; d < 64; ++d) acs = fmaf(qv[d], Kl[j][d], acs);
            s[j] = acs * 0.125f;   // 1/sqrt(64)
            tmax = fmaxf(tmax, s[j]);
        }
        const float m_new = fmaxf(m_run, tmax);
        const float corr = __expf(m_run - m_new);
        l_run *= corr;
        #pragma unroll
        for (int d = 0; d < 64; ++d) acc[d] *= corr;
        #pragma unroll
        for (int j = 0; j < 32; ++j) {
            const float p = __expf(s[j] - m_new);
            l_run += p;
            #pragma unroll
            for (int d = 0; d < 64; ++d) acc[d] = fmaf(p, Vl[j][d], acc[d]);
        }
        m_run = m_new;
    }
    const float inv = 1.0f / l_run;
    float* orow = o + base + (size_t)q * D_MODEL;
    #pragma unroll
    for (int d = 0; d < 64; d += 4) {
        float4 t;
        t.x = acc[d] * inv; t.y = acc[d + 1] * inv;
        t.z = acc[d + 2] * inv; t.w = acc[d + 3] * inv;
        *(float4*)(orow + d) = t;
    }
}

extern "C" void kernel_launch(void* const* d_in, const int* in_sizes, int n_in,
                              void* d_out, int out_size, void* d_ws, size_t ws_size,
                              hipStream_t stream)
{
    const float* x    = (const float*)d_in[0];
    const float* ln1w = (const float*)d_in[1];
    const float* ln1b = (const float*)d_in[2];
    const float* qkvw = (const float*)d_in[3];
    const float* qkvb = (const float*)d_in[4];
    const float* inw  = (const float*)d_in[5];
    const float* inb  = (const float*)d_in[6];
    const float* outw = (const float*)d_in[7];
    const float* outb = (const float*)d_in[8];
    const float* ln2w = (const float*)d_in[9];
    const float* ln2b = (const float*)d_in[10];
    const float* w1   = (const float*)d_in[11];
    const float* b1   = (const float*)d_in[12];
    const float* w2   = (const float*)d_in[13];
    const float* b2   = (const float*)d_in[14];
    float* xo = (float*)d_out;   // running residual stream

    // Workspace layout (fp32): M_ 64MB | Q_ 48MB | R_ 48MB  (total 160MB)
    float* M_ = (float*)d_ws;                        // 4096*4096 (h / o / mlp-mid)
    float* Q_ = M_ + (size_t)TOK * MLP_DIM;          // 4096*3072 (qkv / h2)
    float* R_ = Q_ + (size_t)TOK * 3 * D_MODEL;      // 3 x 4096*1024 (qp,kp,vp)

    hipMemcpyAsync(xo, x, (size_t)TOK * D_MODEL * sizeof(float),
                   hipMemcpyDeviceToDevice, stream);

    const dim3 blk(256);
    for (int i = 0; i < 2; ++i) {
        const float* l_qkvw = qkvw + (size_t)i * D_MODEL * 3 * D_MODEL;
        const float* l_qkvb = qkvb + (size_t)i * 3 * D_MODEL;
        const float* l_inw  = inw  + (size_t)i * D_MODEL * 3 * D_MODEL;
        const float* l_inb  = inb  + (size_t)i * 3 * D_MODEL;
        const float* l_outw = outw + (size_t)i * D_MODEL * D_MODEL;
        const float* l_outb = outb + (size_t)i * D_MODEL;
        const float* l_w1   = w1   + (size_t)i * D_MODEL * MLP_DIM;
        const float* l_b1   = b1   + (size_t)i * MLP_DIM;
        const float* l_w2   = w2   + (size_t)i * MLP_DIM * D_MODEL;
        const float* l_b2   = b2   + (size_t)i * D_MODEL;

        // h = LN1(x)                       -> M_
        ln_kernel<<<TOK, blk, 0, stream>>>(xo, ln1w + i * D_MODEL, ln1b + i * D_MODEL, M_);
        // qkv = h @ qkv_w + qkv_b          -> Q_ [4096,3072]
        sgemm_kernel<F_BIAS><<<dim3(24, 32), blk, 0, stream>>>(
            M_, D_MODEL, l_qkvw, 3 * D_MODEL, l_qkvb, Q_, 3 * D_MODEL, D_MODEL);
        // qp/kp/vp = {q,k,v} @ in_w slices -> R_ [3][4096,1024]
        for (int p = 0; p < 3; ++p) {
            sgemm_kernel<F_BIAS><<<dim3(8, 32), blk, 0, stream>>>(
                Q_ + (size_t)p * D_MODEL, 3 * D_MODEL,
                l_inw + (size_t)p * D_MODEL, 3 * D_MODEL,
                l_inb + (size_t)p * D_MODEL,
                R_ + (size_t)p * TOK * D_MODEL, D_MODEL, D_MODEL);
        }
        // o = attention(qp,kp,vp)          -> M_
        attn_kernel<<<dim3(SEQ / 256, BATCH * NHEADS), blk, 0, stream>>>(
            R_, R_ + (size_t)TOK * D_MODEL, R_ + (size_t)2 * TOK * D_MODEL, M_);
        // x += o @ out_w + out_b           (in-place on xo)
        sgemm_kernel<F_BIAS | F_RESID><<<dim3(8, 32), blk, 0, stream>>>(
            M_, D_MODEL, l_outw, D_MODEL, l_outb, xo, D_MODEL, D_MODEL);
        // h2 = LN2(x)                      -> Q_
        ln_kernel<<<TOK, blk, 0, stream>>>(xo, ln2w + i * D_MODEL, ln2b + i * D_MODEL, Q_);
        // m = gelu(h2 @ w1 + b1)           -> M_ [4096,4096]
        sgemm_kernel<F_BIAS | F_GELU><<<dim3(32, 32), blk, 0, stream>>>(
            Q_, D_MODEL, l_w1, MLP_DIM, l_b1, M_, MLP_DIM, D_MODEL);
        // x += m @ w2 + b2                 (in-place on xo)
        sgemm_kernel<F_BIAS | F_RESID><<<dim3(8, 32), blk, 0, stream>>>(
            M_, MLP_DIM, l_w2, D_MODEL, l_b2, xo, D_MODEL, MLP_DIM);
    }
}

// Round 2
// 4682.968 us; speedup vs baseline: 1.6643x; 1.6643x over previous
//
#include <hip/hip_runtime.h>
#include <math.h>

#define D_MODEL 1024
#define NHEADS 16
#define HEAD_DIM 64
#define SEQ 2048
#define BATCH 2
#define TOK (BATCH*SEQ)     // 4096 tokens
#define MLP_DIM 4096

#define F_BIAS  1
#define F_GELU  2
#define F_RESID 4

typedef __attribute__((ext_vector_type(8))) __bf16 bf16x8;
typedef __attribute__((ext_vector_type(4))) __bf16 bf16x4;
typedef __attribute__((ext_vector_type(4))) float f32x4;

__device__ __forceinline__ void gload16(const void* g, void* l) {
    __builtin_amdgcn_global_load_lds(
        (const __attribute__((address_space(1))) void*)g,
        (__attribute__((address_space(3))) void*)l, 16, 0, 0);
}

// ---------------- weight transpose + fp32->bf16: in[R][C] -> out[C][R] ----------------
__global__ __launch_bounds__(256)
void tconv_kernel(const float* __restrict__ in, __bf16* __restrict__ out, int R, int C)
{
    __shared__ float tile[32][33];
    const int bx = blockIdx.x;          // C/32
    const int by = blockIdx.y;          // R/32
    const int tx = threadIdx.x & 31;
    const int ty = threadIdx.x >> 5;    // 0..7
    #pragma unroll
    for (int i = 0; i < 4; ++i)
        tile[ty * 4 + i][tx] = in[(size_t)(by * 32 + ty * 4 + i) * C + bx * 32 + tx];
    __syncthreads();
    #pragma unroll
    for (int i = 0; i < 4; ++i)
        out[(size_t)(bx * 32 + ty * 4 + i) * R + by * 32 + tx] = (__bf16)tile[tx][ty * 4 + i];
}

// ---------------- LayerNorm: fp32 in, bf16 out ----------------
__global__ __launch_bounds__(256)
void ln_kernel(const float* __restrict__ x, const float* __restrict__ w,
               const float* __restrict__ b, __bf16* __restrict__ out)
{
    const int row = blockIdx.x;
    const int t = threadIdx.x;
    const float* xr = x + (size_t)row * D_MODEL;
    float4 v = *(const float4*)(xr + t * 4);
    float s  = v.x + v.y + v.z + v.w;
    float ss = v.x*v.x + v.y*v.y + v.z*v.z + v.w*v.w;
    #pragma unroll
    for (int off = 32; off > 0; off >>= 1) {
        s  += __shfl_down(s, off);
        ss += __shfl_down(ss, off);
    }
    __shared__ float red[8];
    const int wid = t >> 6, lane = t & 63;
    if (lane == 0) { red[wid] = s; red[4 + wid] = ss; }
    __syncthreads();
    const float st  = red[0] + red[1] + red[2] + red[3];
    const float sst = red[4] + red[5] + red[6] + red[7];
    const float mu  = st * (1.0f / D_MODEL);
    const float var = sst * (1.0f / D_MODEL) - mu * mu;
    const float rs  = rsqrtf(var + 1e-5f);
    const float4 wv = *(const float4*)(w + t * 4);
    const float4 bv = *(const float4*)(b + t * 4);
    bf16x4 o;
    o[0] = (__bf16)((v.x - mu) * rs * wv.x + bv.x);
    o[1] = (__bf16)((v.y - mu) * rs * wv.y + bv.y);
    o[2] = (__bf16)((v.z - mu) * rs * wv.z + bv.z);
    o[3] = (__bf16)((v.w - mu) * rs * wv.w + bv.w);
    *(bf16x4*)(out + (size_t)row * D_MODEL + t * 4) = o;
}

// ---------------- MFMA GEMM: C[M,N] = A[M,K](bf16) @ Bt[N,K]^T(bf16) ----------------
// 128x128 tile, BK=32, 256 thr = 4 waves (2x2), each wave 64x64 = 4x4 frags 16x16x32.
// LDS layout [kc][row][8] (kc = k/8) -> conflict-free ds_read_b128 fragments;
// staged via global_load_lds w/ pre-swizzled per-lane global source.
template<int FLAGS, typename CT>
__global__ __launch_bounds__(256)
void mgemm_kernel(const __bf16* __restrict__ A, int lda,
                  const __bf16* __restrict__ Bt, int ldb,
                  const float* __restrict__ bias,
                  CT* __restrict__ C, int ldc, int K)
{
    __shared__ __bf16 As[512 * 8];   // [4][128][8]
    __shared__ __bf16 Bs[512 * 8];
    const int tid  = threadIdx.x;
    const int lane = tid & 63;
    const int w    = tid >> 6;
    const int wm   = w >> 1, wn = w & 1;
    const int bm = blockIdx.y, bn = blockIdx.x;

    f32x4 acc[4][4];
    #pragma unroll
    for (int i = 0; i < 4; ++i)
        #pragma unroll
        for (int j = 0; j < 4; ++j)
            acc[i][j] = (f32x4){0.f, 0.f, 0.f, 0.f};

    // staging slots: call c covers slots c*256+tid; slot s -> kc=s>>7, row=s&127
    const int s1 = 256 + tid;
    const int kc0 = tid >> 7, r0 = tid & 127;
    const int kc1 = s1  >> 7, r1 = s1 & 127;

    const __bf16* a0p = A  + (size_t)(bm * 128 + r0) * lda + kc0 * 8;
    const __bf16* a1p = A  + (size_t)(bm * 128 + r1) * lda + kc1 * 8;
    const __bf16* b0p = Bt + (size_t)(bn * 128 + r0) * ldb + kc0 * 8;
    const __bf16* b1p = Bt + (size_t)(bn * 128 + r1) * ldb + kc1 * 8;

    __bf16* asl0 = &As[(size_t)(0 * 256 + w * 64) * 8];
    __bf16* asl1 = &As[(size_t)(1 * 256 + w * 64) * 8];
    __bf16* bsl0 = &Bs[(size_t)(0 * 256 + w * 64) * 8];
    __bf16* bsl1 = &Bs[(size_t)(1 * 256 + w * 64) * 8];

    // fragment LDS indices (conflict-free: 16 consecutive 16B per quarter-wave)
    const int kq = lane >> 4;            // k-chunk 0..3
    const int fr = lane & 15;            // row/col within fragment
    const int aidx = (kq * 128 + wm * 64 + fr) * 8;
    const int bidx = (kq * 128 + wn * 64 + fr) * 8;

    for (int k0 = 0; k0 < K; k0 += 32) {
        gload16(a0p + k0, asl0);
        gload16(a1p + k0, asl1);
        gload16(b0p + k0, bsl0);
        gload16(b1p + k0, bsl1);
        __syncthreads();   // drains vmcnt -> LDS tiles ready

        bf16x8 af[4], bfr[4];
        #pragma unroll
        for (int i = 0; i < 4; ++i) {
            af[i]  = *(const bf16x8*)&As[aidx + i * 16 * 8];
            bfr[i] = *(const bf16x8*)&Bs[bidx + i * 16 * 8];
        }
        #pragma unroll
        for (int i = 0; i < 4; ++i)
            #pragma unroll
            for (int j = 0; j < 4; ++j)
                acc[i][j] = __builtin_amdgcn_mfma_f32_16x16x32_bf16(
                    af[i], bfr[j], acc[i][j], 0, 0, 0);
        __syncthreads();   // all reads done before next overwrite
    }

    // epilogue: C/D layout col=lane&15, row=(lane>>4)*4+e  [verified m89]
    const int row0 = bm * 128 + wm * 64 + (lane >> 4) * 4;
    const int col0 = bn * 128 + wn * 64 + (lane & 15);
    #pragma unroll
    for (int i = 0; i < 4; ++i) {
        #pragma unroll
        for (int j = 0; j < 4; ++j) {
            const int col = col0 + j * 16;
            float bb = (FLAGS & F_BIAS) ? bias[col] : 0.0f;
            #pragma unroll
            for (int e = 0; e < 4; ++e) {
                const int row = row0 + i * 16 + e;
                float val = acc[i][j][e] + bb;
                if (FLAGS & F_GELU)
                    val = 0.5f * val * (1.0f + erff(val * 0.70710678118654752f));
                if (FLAGS & F_RESID)
                    val += (float)C[(size_t)row * ldc + col];
                C[(size_t)row * ldc + col] = (CT)val;
            }
        }
    }
}

// ---------------- Attention: thread per q-row, float4 LDS broadcast reads ----------------
__global__ __launch_bounds__(256)
void attn_kernel(const float* __restrict__ qp, const float* __restrict__ kp,
                 const float* __restrict__ vp, __bf16* __restrict__ o)
{
    const int bh = blockIdx.y;
    const int b = bh >> 4;
    const int h = bh & 15;
    const int q = blockIdx.x * 256 + threadIdx.x;
    const size_t base = ((size_t)b * SEQ) * D_MODEL + (size_t)h * HEAD_DIM;
    const float* qrow = qp + base + (size_t)q * D_MODEL;
    const float* Kb = kp + base;
    const float* Vb = vp + base;

    float qv[64];
    #pragma unroll
    for (int d = 0; d < 64; d += 4) {
        float4 t = *(const float4*)(qrow + d);
        qv[d] = t.x; qv[d + 1] = t.y; qv[d + 2] = t.z; qv[d + 3] = t.w;
    }
    float m_run = -1e30f, l_run = 0.0f;
    float acc[64];
    #pragma unroll
    for (int d = 0; d < 64; ++d) acc[d] = 0.0f;

    __shared__ float Kl[32][64];
    __shared__ float Vl[32][64];
    const int lr = threadIdx.x >> 3;        // 0..31
    const int lc = (threadIdx.x & 7) << 3;  // 0..56

    for (int t0 = 0; t0 < SEQ; t0 += 32) {
        __syncthreads();
        const float* Ksrc = Kb + (size_t)(t0 + lr) * D_MODEL + lc;
        const float* Vsrc = Vb + (size_t)(t0 + lr) * D_MODEL + lc;
        *(float4*)&Kl[lr][lc]     = *(const float4*)(Ksrc);
        *(float4*)&Kl[lr][lc + 4] = *(const float4*)(Ksrc + 4);
        *(float4*)&Vl[lr][lc]     = *(const float4*)(Vsrc);
        *(float4*)&Vl[lr][lc + 4] = *(const float4*)(Vsrc + 4);
        __syncthreads();

        float s[32];
        float tmax = -1e30f;
        #pragma unroll
        for (int j = 0; j < 32; ++j) {
            float a0 = 0.f, a1 = 0.f, a2 = 0.f, a3 = 0.f;
            #pragma unroll
            for (int d4 = 0; d4 < 16; ++d4) {
                float4 kv4 = *(const float4*)&Kl[j][d4 * 4];
                a0 = fmaf(qv[d4 * 4 + 0], kv4.x, a0);
                a1 = fmaf(qv[d4 * 4 + 1], kv4.y, a1);
                a2 = fmaf(qv[d4 * 4 + 2], kv4.z, a2);
                a3 = fmaf(qv[d4 * 4 + 3], kv4.w, a3);
            }
            s[j] = ((a0 + a1) + (a2 + a3)) * 0.125f;
            tmax = fmaxf(tmax, s[j]);
        }
        const float m_new = fmaxf(m_run, tmax);
        const float corr = __expf(m_run - m_new);
        l_run *= corr;
        #pragma unroll
        for (int d = 0; d < 64; ++d) acc[d] *= corr;
        #pragma unroll
        for (int j = 0; j < 32; ++j) {
            const float p = __expf(s[j] - m_new);
            l_run += p;
            #pragma unroll
            for (int d4 = 0; d4 < 16; ++d4) {
                float4 v4 = *(const float4*)&Vl[j][d4 * 4];
                acc[d4 * 4 + 0] = fmaf(p, v4.x, acc[d4 * 4 + 0]);
                acc[d4 * 4 + 1] = fmaf(p, v4.y, acc[d4 * 4 + 1]);
                acc[d4 * 4 + 2] = fmaf(p, v4.z, acc[d4 * 4 + 2]);
                acc[d4 * 4 + 3] = fmaf(p, v4.w, acc[d4 * 4 + 3]);
            }
        }
        m_run = m_new;
    }
    const float inv = 1.0f / l_run;
    __bf16* orow = o + base + (size_t)q * D_MODEL;
    #pragma unroll
    for (int d = 0; d < 64; d += 4) {
        bf16x4 t;
        t[0] = (__bf16)(acc[d] * inv);     t[1] = (__bf16)(acc[d + 1] * inv);
        t[2] = (__bf16)(acc[d + 2] * inv); t[3] = (__bf16)(acc[d + 3] * inv);
        *(bf16x4*)(orow + d) = t;
    }
}

extern "C" void kernel_launch(void* const* d_in, const int* in_sizes, int n_in,
                              void* d_out, int out_size, void* d_ws, size_t ws_size,
                              hipStream_t stream)
{
    const float* x    = (const float*)d_in[0];
    const float* ln1w = (const float*)d_in[1];
    const float* ln1b = (const float*)d_in[2];
    const float* qkvw = (const float*)d_in[3];
    const float* qkvb = (const float*)d_in[4];
    const float* inw  = (const float*)d_in[5];
    const float* inb  = (const float*)d_in[6];
    const float* outw = (const float*)d_in[7];
    const float* outb = (const float*)d_in[8];
    const float* ln2w = (const float*)d_in[9];
    const float* ln2b = (const float*)d_in[10];
    const float* w1   = (const float*)d_in[11];
    const float* b1   = (const float*)d_in[12];
    const float* w2   = (const float*)d_in[13];
    const float* b2   = (const float*)d_in[14];
    float* xo = (float*)d_out;   // running residual stream (fp32)

    // ---- workspace layout ----
    // WT: bf16 transposed weights, per layer 15,728,640 el; 2 layers = 62.9MB
    // X8: bf16 [4096,1024] (LN out / attn out)                          8.4MB
    // U : bf16 [4096,4096] (qkv [4096,3072] or mlp-mid [4096,4096])    33.6MB
    // R : fp32 3 x [4096,1024] (qp,kp,vp)                              50.3MB
    __bf16* WT = (__bf16*)d_ws;
    const size_t L_WT = 15728640;
    __bf16* X8 = WT + 2 * L_WT;
    __bf16* U_ = X8 + (size_t)TOK * D_MODEL;
    float*  R_ = (float*)(U_ + (size_t)TOK * MLP_DIM);

    const size_t OFF_QKV = 0;
    const size_t OFF_IN  = 3145728;
    const size_t OFF_OUT = 6291456;
    const size_t OFF_W1  = 7340032;
    const size_t OFF_W2  = 11534336;

    hipMemcpyAsync(xo, x, (size_t)TOK * D_MODEL * sizeof(float),
                   hipMemcpyDeviceToDevice, stream);

    const dim3 blk(256);
    // weight transpose+convert (runs every call; ~180MB traffic)
    for (int i = 0; i < 2; ++i) {
        __bf16* wl = WT + i * L_WT;
        tconv_kernel<<<dim3(3 * D_MODEL / 32, D_MODEL / 32), blk, 0, stream>>>(
            qkvw + (size_t)i * D_MODEL * 3 * D_MODEL, wl + OFF_QKV, D_MODEL, 3 * D_MODEL);
        tconv_kernel<<<dim3(3 * D_MODEL / 32, D_MODEL / 32), blk, 0, stream>>>(
            inw + (size_t)i * D_MODEL * 3 * D_MODEL, wl + OFF_IN, D_MODEL, 3 * D_MODEL);
        tconv_kernel<<<dim3(D_MODEL / 32, D_MODEL / 32), blk, 0, stream>>>(
            outw + (size_t)i * D_MODEL * D_MODEL, wl + OFF_OUT, D_MODEL, D_MODEL);
        tconv_kernel<<<dim3(MLP_DIM / 32, D_MODEL / 32), blk, 0, stream>>>(
            w1 + (size_t)i * D_MODEL * MLP_DIM, wl + OFF_W1, D_MODEL, MLP_DIM);
        tconv_kernel<<<dim3(D_MODEL / 32, MLP_DIM / 32), blk, 0, stream>>>(
            w2 + (size_t)i * MLP_DIM * D_MODEL, wl + OFF_W2, MLP_DIM, D_MODEL);
    }

    for (int i = 0; i < 2; ++i) {
        __bf16* wl = WT + i * L_WT;
        const float* l_qkvb = qkvb + (size_t)i * 3 * D_MODEL;
        const float* l_inb  = inb  + (size_t)i * 3 * D_MODEL;
        const float* l_outb = outb + (size_t)i * D_MODEL;
        const float* l_b1   = b1   + (size_t)i * MLP_DIM;
        const float* l_b2   = b2   + (size_t)i * D_MODEL;

        // h = LN1(x) -> X8 (bf16)
        ln_kernel<<<TOK, blk, 0, stream>>>(xo, ln1w + i * D_MODEL, ln1b + i * D_MODEL, X8);
        // qkv = h @ qkv_w + b -> U_ (bf16 [4096,3072])
        mgemm_kernel<F_BIAS, __bf16><<<dim3(24, 32), blk, 0, stream>>>(
            X8, D_MODEL, wl + OFF_QKV, D_MODEL, l_qkvb, U_, 3 * D_MODEL, D_MODEL);
        // qp/kp/vp -> R_ (fp32)
        for (int p = 0; p < 3; ++p) {
            mgemm_kernel<F_BIAS, float><<<dim3(8, 32), blk, 0, stream>>>(
                U_ + (size_t)p * D_MODEL, 3 * D_MODEL,
                wl + OFF_IN + (size_t)p * D_MODEL * D_MODEL, D_MODEL,
                l_inb + (size_t)p * D_MODEL,
                R_ + (size_t)p * TOK * D_MODEL, D_MODEL, D_MODEL);
        }
        // o = attention -> X8 (bf16)
        attn_kernel<<<dim3(SEQ / 256, BATCH * NHEADS), blk, 0, stream>>>(
            R_, R_ + (size_t)TOK * D_MODEL, R_ + (size_t)2 * TOK * D_MODEL, X8);
        // x += o @ out_w + b
        mgemm_kernel<F_BIAS | F_RESID, float><<<dim3(8, 32), blk, 0, stream>>>(
            X8, D_MODEL, wl + OFF_OUT, D_MODEL, l_outb, xo, D_MODEL, D_MODEL);
        // h2 = LN2(x) -> X8
        ln_kernel<<<TOK, blk, 0, stream>>>(xo, ln2w + i * D_MODEL, ln2b + i * D_MODEL, X8);
        // m = gelu(h2 @ w1 + b1) -> U_ (bf16 [4096,4096])
        mgemm_kernel<F_BIAS | F_GELU, __bf16><<<dim3(32, 32), blk, 0, stream>>>(
            X8, D_MODEL, wl + OFF_W1, D_MODEL, l_b1, U_, MLP_DIM, D_MODEL);
        // x += m @ w2 + b2
        mgemm_kernel<F_BIAS | F_RESID, float><<<dim3(8, 32), blk, 0, stream>>>(
            U_, MLP_DIM, wl + OFF_W2, MLP_DIM, l_b2, xo, D_MODEL, MLP_DIM);
    }
}

// Round 3
// 1193.223 us; speedup vs baseline: 6.5320x; 3.9246x over previous
//
#include <hip/hip_runtime.h>
#include <math.h>

#define D_MODEL 1024
#define NHEADS 16
#define HEAD_DIM 64
#define SEQ 2048
#define BATCH 2
#define TOK (BATCH*SEQ)     // 4096 tokens
#define MLP_DIM 4096

#define F_BIAS  1
#define F_GELU  2
#define F_RESID 4

typedef __attribute__((ext_vector_type(8))) __bf16 bf16x8;
typedef __attribute__((ext_vector_type(4))) __bf16 bf16x4;
typedef __attribute__((ext_vector_type(4))) float f32x4;

__device__ __forceinline__ void gload16(const void* g, void* l) {
    __builtin_amdgcn_global_load_lds(
        (const __attribute__((address_space(1))) void*)g,
        (__attribute__((address_space(3))) void*)l, 16, 0, 0);
}

// ---------------- weight transpose + fp32->bf16: in[R][C] -> out[C][R] ----------------
__global__ __launch_bounds__(256)
void tconv_kernel(const float* __restrict__ in, __bf16* __restrict__ out, int R, int C)
{
    __shared__ float tile[32][33];
    const int bx = blockIdx.x;          // C/32
    const int by = blockIdx.y;          // R/32
    const int tx = threadIdx.x & 31;
    const int ty = threadIdx.x >> 5;    // 0..7
    #pragma unroll
    for (int i = 0; i < 4; ++i)
        tile[ty * 4 + i][tx] = in[(size_t)(by * 32 + ty * 4 + i) * C + bx * 32 + tx];
    __syncthreads();
    #pragma unroll
    for (int i = 0; i < 4; ++i)
        out[(size_t)(bx * 32 + ty * 4 + i) * R + by * 32 + tx] = (__bf16)tile[tx][ty * 4 + i];
}

// ---------------- V transpose: v[b*S+s][h*64+d](bf16) -> vt[bh][d][s](bf16) ----------
__global__ __launch_bounds__(256)
void tv_kernel(const __bf16* __restrict__ v, __bf16* __restrict__ vt)
{
    __shared__ __bf16 t[64][72];
    const int bh = blockIdx.y, b = bh >> 4, h = bh & 15;
    const int s0 = blockIdx.x * 64;
    const int r = threadIdx.x >> 3;         // 0..31
    const int c = (threadIdx.x & 7) * 8;    // 0..56
    #pragma unroll
    for (int rr = 0; rr < 64; rr += 32) {
        bf16x8 x = *(const bf16x8*)&v[(size_t)(b * SEQ + s0 + r + rr) * D_MODEL + h * 64 + c];
        #pragma unroll
        for (int k = 0; k < 8; ++k) t[r + rr][c + k] = x[k];
    }
    __syncthreads();
    #pragma unroll
    for (int rr = 0; rr < 64; rr += 32) {
        bf16x8 y;
        #pragma unroll
        for (int k = 0; k < 8; ++k) y[k] = t[c + k][r + rr];
        *(bf16x8*)&vt[((size_t)bh * 64 + r + rr) * SEQ + s0 + c] = y;
    }
}

// ---------------- LayerNorm: fp32 in, bf16 out ----------------
__global__ __launch_bounds__(256)
void ln_kernel(const float* __restrict__ x, const float* __restrict__ w,
               const float* __restrict__ b, __bf16* __restrict__ out)
{
    const int row = blockIdx.x;
    const int t = threadIdx.x;
    const float* xr = x + (size_t)row * D_MODEL;
    float4 v = *(const float4*)(xr + t * 4);
    float s  = v.x + v.y + v.z + v.w;
    float ss = v.x*v.x + v.y*v.y + v.z*v.z + v.w*v.w;
    #pragma unroll
    for (int off = 32; off > 0; off >>= 1) {
        s  += __shfl_down(s, off);
        ss += __shfl_down(ss, off);
    }
    __shared__ float red[8];
    const int wid = t >> 6, lane = t & 63;
    if (lane == 0) { red[wid] = s; red[4 + wid] = ss; }
    __syncthreads();
    const float st  = red[0] + red[1] + red[2] + red[3];
    const float sst = red[4] + red[5] + red[6] + red[7];
    const float mu  = st * (1.0f / D_MODEL);
    const float var = sst * (1.0f / D_MODEL) - mu * mu;
    const float rs  = rsqrtf(var + 1e-5f);
    const float4 wv = *(const float4*)(w + t * 4);
    const float4 bv = *(const float4*)(b + t * 4);
    bf16x4 o;
    o[0] = (__bf16)((v.x - mu) * rs * wv.x + bv.x);
    o[1] = (__bf16)((v.y - mu) * rs * wv.y + bv.y);
    o[2] = (__bf16)((v.z - mu) * rs * wv.z + bv.z);
    o[3] = (__bf16)((v.w - mu) * rs * wv.w + bv.w);
    *(bf16x4*)(out + (size_t)row * D_MODEL + t * 4) = o;
}

// ---------------- MFMA GEMM (unchanged from round 2) ----------------
template<int FLAGS, typename CT>
__global__ __launch_bounds__(256)
void mgemm_kernel(const __bf16* __restrict__ A, int lda,
                  const __bf16* __restrict__ Bt, int ldb,
                  const float* __restrict__ bias,
                  CT* __restrict__ C, int ldc, int K)
{
    __shared__ __bf16 As[512 * 8];   // [4][128][8]
    __shared__ __bf16 Bs[512 * 8];
    const int tid  = threadIdx.x;
    const int lane = tid & 63;
    const int w    = tid >> 6;
    const int wm   = w >> 1, wn = w & 1;
    const int bm = blockIdx.y, bn = blockIdx.x;

    f32x4 acc[4][4];
    #pragma unroll
    for (int i = 0; i < 4; ++i)
        #pragma unroll
        for (int j = 0; j < 4; ++j)
            acc[i][j] = (f32x4){0.f, 0.f, 0.f, 0.f};

    const int s1 = 256 + tid;
    const int kc0 = tid >> 7, r0 = tid & 127;
    const int kc1 = s1  >> 7, r1 = s1 & 127;

    const __bf16* a0p = A  + (size_t)(bm * 128 + r0) * lda + kc0 * 8;
    const __bf16* a1p = A  + (size_t)(bm * 128 + r1) * lda + kc1 * 8;
    const __bf16* b0p = Bt + (size_t)(bn * 128 + r0) * ldb + kc0 * 8;
    const __bf16* b1p = Bt + (size_t)(bn * 128 + r1) * ldb + kc1 * 8;

    __bf16* asl0 = &As[(size_t)(0 * 256 + w * 64) * 8];
    __bf16* asl1 = &As[(size_t)(1 * 256 + w * 64) * 8];
    __bf16* bsl0 = &Bs[(size_t)(0 * 256 + w * 64) * 8];
    __bf16* bsl1 = &Bs[(size_t)(1 * 256 + w * 64) * 8];

    const int kq = lane >> 4;
    const int fr = lane & 15;
    const int aidx = (kq * 128 + wm * 64 + fr) * 8;
    const int bidx = (kq * 128 + wn * 64 + fr) * 8;

    for (int k0 = 0; k0 < K; k0 += 32) {
        gload16(a0p + k0, asl0);
        gload16(a1p + k0, asl1);
        gload16(b0p + k0, bsl0);
        gload16(b1p + k0, bsl1);
        __syncthreads();

        bf16x8 af[4], bfr[4];
        #pragma unroll
        for (int i = 0; i < 4; ++i) {
            af[i]  = *(const bf16x8*)&As[aidx + i * 16 * 8];
            bfr[i] = *(const bf16x8*)&Bs[bidx + i * 16 * 8];
        }
        #pragma unroll
        for (int i = 0; i < 4; ++i)
            #pragma unroll
            for (int j = 0; j < 4; ++j)
                acc[i][j] = __builtin_amdgcn_mfma_f32_16x16x32_bf16(
                    af[i], bfr[j], acc[i][j], 0, 0, 0);
        __syncthreads();
    }

    const int row0 = bm * 128 + wm * 64 + (lane >> 4) * 4;
    const int col0 = bn * 128 + wn * 64 + (lane & 15);
    #pragma unroll
    for (int i = 0; i < 4; ++i) {
        #pragma unroll
        for (int j = 0; j < 4; ++j) {
            const int col = col0 + j * 16;
            float bb = (FLAGS & F_BIAS) ? bias[col] : 0.0f;
            #pragma unroll
            for (int e = 0; e < 4; ++e) {
                const int row = row0 + i * 16 + e;
                float val = acc[i][j][e] + bb;
                if (FLAGS & F_GELU)
                    val = 0.5f * val * (1.0f + erff(val * 0.70710678118654752f));
                if (FLAGS & F_RESID)
                    val += (float)C[(size_t)row * ldc + col];
                C[(size_t)row * ldc + col] = (CT)val;
            }
        }
    }
}

// ---------------- MFMA flash attention ----------------
// grid (S/64, B*H), 256 thr = 4 waves; wave w owns q rows [q0+w*16, q0+w*16+16).
// KV tiles of 128: K staged [kc=d/8][kv][8], Vt staged [kc=kv/8][d][8];
// S=Q@K^T via mfma (acc: row=q=(lane>>4)*4+e, col=kv=j*16+(lane&15));
// softmax reduced with shfl_xor over the 16-lane col group; P->LDS (A-frag
// layout) -> PV mfma with V fragments read contiguously from transposed V.
__global__ __launch_bounds__(256)
void attn2_kernel(const __bf16* __restrict__ qp, const __bf16* __restrict__ kp,
                  const __bf16* __restrict__ vt, __bf16* __restrict__ o)
{
    const int bh = blockIdx.y;
    const int b = bh >> 4, h = bh & 15;
    const int tid = threadIdx.x;
    const int lane = tid & 63;
    const int w = tid >> 6;
    const int fr = lane & 15;
    const int kq = lane >> 4;
    const int q0 = blockIdx.x * 64 + w * 16;

    __shared__ __align__(16) __bf16 Ks[8 * 128 * 8];    // 16 KB
    __shared__ __align__(16) __bf16 Vs[16 * 64 * 8];    // 16 KB
    __shared__ __align__(16) __bf16 Ps[4][16 * 16 * 8]; // 4 x 4 KB

    // Q fragments (A-frag): row=q0+fr, k=d=mc*32+kq*8+e
    const __bf16* qb = qp + (size_t)(b * SEQ + q0 + fr) * D_MODEL + h * HEAD_DIM;
    const bf16x8 qf0 = *(const bf16x8*)(qb + kq * 8);
    const bf16x8 qf1 = *(const bf16x8*)(qb + 32 + kq * 8);

    const __bf16* kb = kp + (size_t)(b * SEQ) * D_MODEL + h * HEAD_DIM;
    const __bf16* vb = vt + (size_t)bh * HEAD_DIM * SEQ;

    f32x4 acc_o[4];
    #pragma unroll
    for (int dj = 0; dj < 4; ++dj) acc_o[dj] = (f32x4){0.f, 0.f, 0.f, 0.f};
    float m_run[4], l_run[4];
    #pragma unroll
    for (int e = 0; e < 4; ++e) { m_run[e] = -1e30f; l_run[e] = 0.f; }

    for (int kv0 = 0; kv0 < SEQ; kv0 += 128) {
        __syncthreads();   // all waves done reading previous K/V tile
        #pragma unroll
        for (int c = 0; c < 4; ++c) {
            const int s = c * 256 + tid;
            gload16(kb + (size_t)(kv0 + (s & 127)) * D_MODEL + (s >> 7) * 8,
                    &Ks[(size_t)(c * 256 + w * 64) * 8]);
        }
        #pragma unroll
        for (int c = 0; c < 4; ++c) {
            const int s = c * 256 + tid;
            gload16(vb + (size_t)(s & 63) * SEQ + kv0 + (s >> 6) * 8,
                    &Vs[(size_t)(c * 256 + w * 64) * 8]);
        }
        __syncthreads();   // drains vmcnt -> tiles ready

        // ---- S = Q @ K^T  (8 col-frags of 16 kv each) ----
        f32x4 sacc[8];
        #pragma unroll
        for (int j = 0; j < 8; ++j) {
            const bf16x8 kf0 = *(const bf16x8*)&Ks[((0 * 4 + kq) * 128 + j * 16 + fr) * 8];
            const bf16x8 kf1 = *(const bf16x8*)&Ks[((1 * 4 + kq) * 128 + j * 16 + fr) * 8];
            sacc[j] = __builtin_amdgcn_mfma_f32_16x16x32_bf16(
                qf0, kf0, (f32x4){0.f, 0.f, 0.f, 0.f}, 0, 0, 0);
            sacc[j] = __builtin_amdgcn_mfma_f32_16x16x32_bf16(qf1, kf1, sacc[j], 0, 0, 0);
        }

        // ---- online softmax over rows q = kq*4+e ----
        #pragma unroll
        for (int e = 0; e < 4; ++e) {
            float mx = sacc[0][e];
            #pragma unroll
            for (int j = 1; j < 8; ++j) mx = fmaxf(mx, sacc[j][e]);
            mx *= 0.125f;
            #pragma unroll
            for (int off = 1; off < 16; off <<= 1)
                mx = fmaxf(mx, __shfl_xor(mx, off));
            const float m_new = fmaxf(m_run[e], mx);
            const float corr = __expf(m_run[e] - m_new);
            float sum = 0.f;
            #pragma unroll
            for (int j = 0; j < 8; ++j) {
                const float p = __expf(sacc[j][e] * 0.125f - m_new);
                sum += p;
                Ps[w][((j * 2 + (fr >> 3)) * 16 + kq * 4 + e) * 8 + (fr & 7)] = (__bf16)p;
            }
            #pragma unroll
            for (int off = 1; off < 16; off <<= 1)
                sum += __shfl_xor(sum, off);
            l_run[e] = l_run[e] * corr + sum;
            m_run[e] = m_new;
            #pragma unroll
            for (int dj = 0; dj < 4; ++dj) acc_o[dj][e] *= corr;
        }

        // ---- O += P @ V ----
        #pragma unroll
        for (int m = 0; m < 4; ++m) {
            const bf16x8 pf = *(const bf16x8*)&Ps[w][((m * 4 + kq) * 16 + fr) * 8];
            #pragma unroll
            for (int dj = 0; dj < 4; ++dj) {
                const bf16x8 vf = *(const bf16x8*)&Vs[((m * 4 + kq) * 64 + dj * 16 + fr) * 8];
                acc_o[dj] = __builtin_amdgcn_mfma_f32_16x16x32_bf16(pf, vf, acc_o[dj], 0, 0, 0);
            }
        }
    }

    // epilogue: row=q0+kq*4+e, col=h*64+dj*16+fr
    #pragma unroll
    for (int e = 0; e < 4; ++e) {
        const float inv = 1.0f / l_run[e];
        const size_t rb = (size_t)(b * SEQ + q0 + kq * 4 + e) * D_MODEL + h * HEAD_DIM;
        #pragma unroll
        for (int dj = 0; dj < 4; ++dj)
            o[rb + dj * 16 + fr] = (__bf16)(acc_o[dj][e] * inv);
    }
}

extern "C" void kernel_launch(void* const* d_in, const int* in_sizes, int n_in,
                              void* d_out, int out_size, void* d_ws, size_t ws_size,
                              hipStream_t stream)
{
    const float* x    = (const float*)d_in[0];
    const float* ln1w = (const float*)d_in[1];
    const float* ln1b = (const float*)d_in[2];
    const float* qkvw = (const float*)d_in[3];
    const float* qkvb = (const float*)d_in[4];
    const float* inw  = (const float*)d_in[5];
    const float* inb  = (const float*)d_in[6];
    const float* outw = (const float*)d_in[7];
    const float* outb = (const float*)d_in[8];
    const float* ln2w = (const float*)d_in[9];
    const float* ln2b = (const float*)d_in[10];
    const float* w1   = (const float*)d_in[11];
    const float* b1   = (const float*)d_in[12];
    const float* w2   = (const float*)d_in[13];
    const float* b2   = (const float*)d_in[14];
    float* xo = (float*)d_out;   // running residual stream (fp32)

    // ---- workspace layout (bf16 elements) ----
    __bf16* WT = (__bf16*)d_ws;
    const size_t L_WT = 15728640;                    // per-layer transposed weights
    __bf16* X8 = WT + 2 * L_WT;                      // [4096,1024] LN out / attn out
    __bf16* U_ = X8 + (size_t)TOK * D_MODEL;         // [4096,4096] qkv / mlp-mid
    __bf16* Qb = U_ + (size_t)TOK * MLP_DIM;         // [4096,1024]
    __bf16* Kb = Qb + (size_t)TOK * D_MODEL;         // [4096,1024]
    __bf16* Vb = Kb + (size_t)TOK * D_MODEL;         // [4096,1024]
    __bf16* VT = Vb + (size_t)TOK * D_MODEL;         // [32][64][2048] transposed V

    const size_t OFF_QKV = 0;
    const size_t OFF_IN  = 3145728;
    const size_t OFF_OUT = 6291456;
    const size_t OFF_W1  = 7340032;
    const size_t OFF_W2  = 11534336;

    hipMemcpyAsync(xo, x, (size_t)TOK * D_MODEL * sizeof(float),
                   hipMemcpyDeviceToDevice, stream);

    const dim3 blk(256);
    for (int i = 0; i < 2; ++i) {
        __bf16* wl = WT + i * L_WT;
        tconv_kernel<<<dim3(3 * D_MODEL / 32, D_MODEL / 32), blk, 0, stream>>>(
            qkvw + (size_t)i * D_MODEL * 3 * D_MODEL, wl + OFF_QKV, D_MODEL, 3 * D_MODEL);
        tconv_kernel<<<dim3(3 * D_MODEL / 32, D_MODEL / 32), blk, 0, stream>>>(
            inw + (size_t)i * D_MODEL * 3 * D_MODEL, wl + OFF_IN, D_MODEL, 3 * D_MODEL);
        tconv_kernel<<<dim3(D_MODEL / 32, D_MODEL / 32), blk, 0, stream>>>(
            outw + (size_t)i * D_MODEL * D_MODEL, wl + OFF_OUT, D_MODEL, D_MODEL);
        tconv_kernel<<<dim3(MLP_DIM / 32, D_MODEL / 32), blk, 0, stream>>>(
            w1 + (size_t)i * D_MODEL * MLP_DIM, wl + OFF_W1, D_MODEL, MLP_DIM);
        tconv_kernel<<<dim3(D_MODEL / 32, MLP_DIM / 32), blk, 0, stream>>>(
            w2 + (size_t)i * MLP_DIM * D_MODEL, wl + OFF_W2, MLP_DIM, D_MODEL);
    }

    for (int i = 0; i < 2; ++i) {
        __bf16* wl = WT + i * L_WT;
        const float* l_qkvb = qkvb + (size_t)i * 3 * D_MODEL;
        const float* l_inb  = inb  + (size_t)i * 3 * D_MODEL;
        const float* l_outb = outb + (size_t)i * D_MODEL;
        const float* l_b1   = b1   + (size_t)i * MLP_DIM;
        const float* l_b2   = b2   + (size_t)i * D_MODEL;

        // h = LN1(x) -> X8
        ln_kernel<<<TOK, blk, 0, stream>>>(xo, ln1w + i * D_MODEL, ln1b + i * D_MODEL, X8);
        // qkv = h @ qkv_w + b -> U_ [4096,3072]
        mgemm_kernel<F_BIAS, __bf16><<<dim3(24, 32), blk, 0, stream>>>(
            X8, D_MODEL, wl + OFF_QKV, D_MODEL, l_qkvb, U_, 3 * D_MODEL, D_MODEL);
        // qp/kp/vp -> Qb/Kb/Vb (bf16)
        __bf16* dsts[3] = {Qb, Kb, Vb};
        for (int p = 0; p < 3; ++p) {
            mgemm_kernel<F_BIAS, __bf16><<<dim3(8, 32), blk, 0, stream>>>(
                U_ + (size_t)p * D_MODEL, 3 * D_MODEL,
                wl + OFF_IN + (size_t)p * D_MODEL * D_MODEL, D_MODEL,
                l_inb + (size_t)p * D_MODEL, dsts[p], D_MODEL, D_MODEL);
        }
        // VT = transpose(Vb)
        tv_kernel<<<dim3(SEQ / 64, BATCH * NHEADS), blk, 0, stream>>>(Vb, VT);
        // o = flashattn(Qb, Kb, VT) -> X8
        attn2_kernel<<<dim3(SEQ / 64, BATCH * NHEADS), blk, 0, stream>>>(Qb, Kb, VT, X8);
        // x += o @ out_w + b
        mgemm_kernel<F_BIAS | F_RESID, float><<<dim3(8, 32), blk, 0, stream>>>(
            X8, D_MODEL, wl + OFF_OUT, D_MODEL, l_outb, xo, D_MODEL, D_MODEL);
        // h2 = LN2(x) -> X8
        ln_kernel<<<TOK, blk, 0, stream>>>(xo, ln2w + i * D_MODEL, ln2b + i * D_MODEL, X8);
        // m = gelu(h2 @ w1 + b1) -> U_ [4096,4096]
        mgemm_kernel<F_BIAS | F_GELU, __bf16><<<dim3(32, 32), blk, 0, stream>>>(
            X8, D_MODEL, wl + OFF_W1, D_MODEL, l_b1, U_, MLP_DIM, D_MODEL);
        // x += m @ w2 + b2
        mgemm_kernel<F_BIAS | F_RESID, float><<<dim3(8, 32), blk, 0, stream>>>(
            U_, MLP_DIM, wl + OFF_W2, MLP_DIM, l_b2, xo, D_MODEL, MLP_DIM);
    }
}

// Round 4
// 1120.628 us; speedup vs baseline: 6.9551x; 1.0648x over previous
//
#include <hip/hip_runtime.h>
#include <math.h>

#define D_MODEL 1024
#define NHEADS 16
#define HEAD_DIM 64
#define SEQ 2048
#define BATCH 2
#define TOK (BATCH*SEQ)     // 4096 tokens
#define MLP_DIM 4096

#define F_BIAS  1
#define F_GELU  2
#define F_RESID 4

typedef __attribute__((ext_vector_type(8))) __bf16 bf16x8;
typedef __attribute__((ext_vector_type(4))) __bf16 bf16x4;
typedef __attribute__((ext_vector_type(4))) float f32x4;

__device__ __forceinline__ void gload16(const void* g, void* l) {
    __builtin_amdgcn_global_load_lds(
        (const __attribute__((address_space(1))) void*)g,
        (__attribute__((address_space(3))) void*)l, 16, 0, 0);
}

// ---------------- flat fp32 -> bf16 convert ----------------
__global__ __launch_bounds__(256)
void conv_kernel(const float* __restrict__ in, __bf16* __restrict__ out, int n8)
{
    const int idx = blockIdx.x * 256 + threadIdx.x;
    if (idx >= n8) return;
    const float4 a = *(const float4*)(in + idx * 8);
    const float4 b = *(const float4*)(in + idx * 8 + 4);
    bf16x8 o;
    o[0] = (__bf16)a.x; o[1] = (__bf16)a.y; o[2] = (__bf16)a.z; o[3] = (__bf16)a.w;
    o[4] = (__bf16)b.x; o[5] = (__bf16)b.y; o[6] = (__bf16)b.z; o[7] = (__bf16)b.w;
    *(bf16x8*)(out + idx * 8) = o;
}

// ---------------- weight transpose + fp32->bf16: in[R][C] -> out[C][R] ----------------
__global__ __launch_bounds__(256)
void tconv_kernel(const float* __restrict__ in, __bf16* __restrict__ out, int R, int C)
{
    __shared__ float tile[32][33];
    const int bx = blockIdx.x;          // C/32
    const int by = blockIdx.y;          // R/32
    const int tx = threadIdx.x & 31;
    const int ty = threadIdx.x >> 5;    // 0..7
    #pragma unroll
    for (int i = 0; i < 4; ++i)
        tile[ty * 4 + i][tx] = in[(size_t)(by * 32 + ty * 4 + i) * C + bx * 32 + tx];
    __syncthreads();
    #pragma unroll
    for (int i = 0; i < 4; ++i)
        out[(size_t)(bx * 32 + ty * 4 + i) * R + by * 32 + tx] = (__bf16)tile[tx][ty * 4 + i];
}

// ---------------- combined bias: bc[p][n] = in_b[p*D+n] + sum_k qkv_b[p*D+k]*in_w[k][p*D+n]
__global__ __launch_bounds__(256)
void bcomb_kernel(const float* __restrict__ qkv_b, const float* __restrict__ in_w,
                  const float* __restrict__ in_b, float* __restrict__ bc)
{
    const int t = blockIdx.x * 256 + threadIdx.x;   // 0..3071
    const int p = t >> 10, n = t & 1023;
    float s = in_b[t];
    #pragma unroll 16
    for (int k = 0; k < D_MODEL; ++k)
        s = fmaf(qkv_b[p * D_MODEL + k], in_w[(size_t)k * 3 * D_MODEL + p * D_MODEL + n], s);
    bc[t] = s;
}

// ---------------- V transpose: v[b*S+s][h*64+d](bf16) -> vt[bh][d][s](bf16) ----------
__global__ __launch_bounds__(256)
void tv_kernel(const __bf16* __restrict__ v, __bf16* __restrict__ vt)
{
    __shared__ __bf16 t[64][72];
    const int bh = blockIdx.y, b = bh >> 4, h = bh & 15;
    const int s0 = blockIdx.x * 64;
    const int r = threadIdx.x >> 3;         // 0..31
    const int c = (threadIdx.x & 7) * 8;    // 0..56
    #pragma unroll
    for (int rr = 0; rr < 64; rr += 32) {
        bf16x8 x = *(const bf16x8*)&v[(size_t)(b * SEQ + s0 + r + rr) * D_MODEL + h * 64 + c];
        #pragma unroll
        for (int k = 0; k < 8; ++k) t[r + rr][c + k] = x[k];
    }
    __syncthreads();
    #pragma unroll
    for (int rr = 0; rr < 64; rr += 32) {
        bf16x8 y;
        #pragma unroll
        for (int k = 0; k < 8; ++k) y[k] = t[c + k][r + rr];
        *(bf16x8*)&vt[((size_t)bh * 64 + r + rr) * SEQ + s0 + c] = y;
    }
}

// ---------------- LayerNorm: fp32 in, bf16 out ----------------
__global__ __launch_bounds__(256)
void ln_kernel(const float* __restrict__ x, const float* __restrict__ w,
               const float* __restrict__ b, __bf16* __restrict__ out)
{
    const int row = blockIdx.x;
    const int t = threadIdx.x;
    const float* xr = x + (size_t)row * D_MODEL;
    float4 v = *(const float4*)(xr + t * 4);
    float s  = v.x + v.y + v.z + v.w;
    float ss = v.x*v.x + v.y*v.y + v.z*v.z + v.w*v.w;
    #pragma unroll
    for (int off = 32; off > 0; off >>= 1) {
        s  += __shfl_down(s, off);
        ss += __shfl_down(ss, off);
    }
    __shared__ float red[8];
    const int wid = t >> 6, lane = t & 63;
    if (lane == 0) { red[wid] = s; red[4 + wid] = ss; }
    __syncthreads();
    const float st  = red[0] + red[1] + red[2] + red[3];
    const float sst = red[4] + red[5] + red[6] + red[7];
    const float mu  = st * (1.0f / D_MODEL);
    const float var = sst * (1.0f / D_MODEL) - mu * mu;
    const float rs  = rsqrtf(var + 1e-5f);
    const float4 wv = *(const float4*)(w + t * 4);
    const float4 bv = *(const float4*)(b + t * 4);
    bf16x4 o;
    o[0] = (__bf16)((v.x - mu) * rs * wv.x + bv.x);
    o[1] = (__bf16)((v.y - mu) * rs * wv.y + bv.y);
    o[2] = (__bf16)((v.z - mu) * rs * wv.z + bv.z);
    o[3] = (__bf16)((v.w - mu) * rs * wv.w + bv.w);
    *(bf16x4*)(out + (size_t)row * D_MODEL + t * 4) = o;
}

// ---------------- MFMA GEMM core: 128x128 tile, BK=32, 4 waves, 4x4 frags/wave ------
__device__ __forceinline__ void mgemm_acc(
    const __bf16* __restrict__ A, int lda,
    const __bf16* __restrict__ Bt, int ldb, int K,
    __bf16* As, __bf16* Bs, f32x4 (&acc)[4][4])
{
    const int tid  = threadIdx.x;
    const int lane = tid & 63;
    const int w    = tid >> 6;
    const int wm   = w >> 1, wn = w & 1;
    const int bm = blockIdx.y, bn = blockIdx.x;

    const int s1 = 256 + tid;
    const int kc0 = tid >> 7, r0 = tid & 127;
    const int kc1 = s1  >> 7, r1 = s1 & 127;

    const __bf16* a0p = A  + (size_t)(bm * 128 + r0) * lda + kc0 * 8;
    const __bf16* a1p = A  + (size_t)(bm * 128 + r1) * lda + kc1 * 8;
    const __bf16* b0p = Bt + (size_t)(bn * 128 + r0) * ldb + kc0 * 8;
    const __bf16* b1p = Bt + (size_t)(bn * 128 + r1) * ldb + kc1 * 8;

    __bf16* asl0 = &As[(size_t)(0 * 256 + w * 64) * 8];
    __bf16* asl1 = &As[(size_t)(1 * 256 + w * 64) * 8];
    __bf16* bsl0 = &Bs[(size_t)(0 * 256 + w * 64) * 8];
    __bf16* bsl1 = &Bs[(size_t)(1 * 256 + w * 64) * 8];

    const int kq = lane >> 4;
    const int fr = lane & 15;
    const int aidx = (kq * 128 + wm * 64 + fr) * 8;
    const int bidx = (kq * 128 + wn * 64 + fr) * 8;

    for (int k0 = 0; k0 < K; k0 += 32) {
        gload16(a0p + k0, asl0);
        gload16(a1p + k0, asl1);
        gload16(b0p + k0, bsl0);
        gload16(b1p + k0, bsl1);
        __syncthreads();

        bf16x8 af[4], bfr[4];
        #pragma unroll
        for (int i = 0; i < 4; ++i) {
            af[i]  = *(const bf16x8*)&As[aidx + i * 16 * 8];
            bfr[i] = *(const bf16x8*)&Bs[bidx + i * 16 * 8];
        }
        #pragma unroll
        for (int i = 0; i < 4; ++i)
            #pragma unroll
            for (int j = 0; j < 4; ++j)
                acc[i][j] = __builtin_amdgcn_mfma_f32_16x16x32_bf16(
                    af[i], bfr[j], acc[i][j], 0, 0, 0);
        __syncthreads();
    }
}

// ---------------- generic z-batched GEMM: per-z operand strides ----------------
template<int FLAGS, typename CT>
__global__ __launch_bounds__(256)
void mgemm_z(const __bf16* __restrict__ A, int lda, long long sAz,
             const __bf16* __restrict__ Bt, int ldb, long long sBz,
             const float* __restrict__ bias, long long sbz,
             CT* __restrict__ C, int ldc, long long sCz, int K)
{
    __shared__ __bf16 As[512 * 8];
    __shared__ __bf16 Bs[512 * 8];
    const int z = blockIdx.z;
    A  += (size_t)z * sAz;
    Bt += (size_t)z * sBz;
    C  += (size_t)z * sCz;
    if (FLAGS & F_BIAS) bias += (size_t)z * sbz;

    f32x4 acc[4][4];
    #pragma unroll
    for (int i = 0; i < 4; ++i)
        #pragma unroll
        for (int j = 0; j < 4; ++j)
            acc[i][j] = (f32x4){0.f, 0.f, 0.f, 0.f};

    mgemm_acc(A, lda, Bt, ldb, K, As, Bs, acc);

    const int lane = threadIdx.x & 63;
    const int w    = threadIdx.x >> 6;
    const int row0 = blockIdx.y * 128 + (w >> 1) * 64 + (lane >> 4) * 4;
    const int col0 = blockIdx.x * 128 + (w & 1) * 64 + (lane & 15);
    #pragma unroll
    for (int i = 0; i < 4; ++i) {
        #pragma unroll
        for (int j = 0; j < 4; ++j) {
            const int col = col0 + j * 16;
            float bb = (FLAGS & F_BIAS) ? bias[col] : 0.0f;
            #pragma unroll
            for (int e = 0; e < 4; ++e) {
                const int row = row0 + i * 16 + e;
                float val = acc[i][j][e] + bb;
                if (FLAGS & F_GELU)
                    val = 0.5f * val * (1.0f + erff(val * 0.70710678118654752f));
                if (FLAGS & F_RESID)
                    val += (float)C[(size_t)row * ldc + col];
                C[(size_t)row * ldc + col] = (CT)val;
            }
        }
    }
}

// ---------------- split-K GEMM: z = k-slice, fp32 atomicAdd epilogue ----------------
__global__ __launch_bounds__(256)
void mgemm_splitk(const __bf16* __restrict__ A, int lda,
                  const __bf16* __restrict__ Bt, int ldb,
                  const float* __restrict__ bias,
                  float* __restrict__ C, int ldc, int KS)
{
    __shared__ __bf16 As[512 * 8];
    __shared__ __bf16 Bs[512 * 8];
    const int z = blockIdx.z;
    A  += (size_t)z * KS;
    Bt += (size_t)z * KS;

    f32x4 acc[4][4];
    #pragma unroll
    for (int i = 0; i < 4; ++i)
        #pragma unroll
        for (int j = 0; j < 4; ++j)
            acc[i][j] = (f32x4){0.f, 0.f, 0.f, 0.f};

    mgemm_acc(A, lda, Bt, ldb, KS, As, Bs, acc);

    const int lane = threadIdx.x & 63;
    const int w    = threadIdx.x >> 6;
    const int row0 = blockIdx.y * 128 + (w >> 1) * 64 + (lane >> 4) * 4;
    const int col0 = blockIdx.x * 128 + (w & 1) * 64 + (lane & 15);
    #pragma unroll
    for (int i = 0; i < 4; ++i) {
        #pragma unroll
        for (int j = 0; j < 4; ++j) {
            const int col = col0 + j * 16;
            const float bb = (z == 0) ? bias[col] : 0.0f;
            #pragma unroll
            for (int e = 0; e < 4; ++e) {
                const int row = row0 + i * 16 + e;
                atomicAdd(&C[(size_t)row * ldc + col], acc[i][j][e] + bb);
            }
        }
    }
}

// ---------------- MFMA flash attention (unchanged from round 3) ----------------
__global__ __launch_bounds__(256)
void attn2_kernel(const __bf16* __restrict__ qp, const __bf16* __restrict__ kp,
                  const __bf16* __restrict__ vt, __bf16* __restrict__ o)
{
    const int bh = blockIdx.y;
    const int b = bh >> 4, h = bh & 15;
    const int tid = threadIdx.x;
    const int lane = tid & 63;
    const int w = tid >> 6;
    const int fr = lane & 15;
    const int kq = lane >> 4;
    const int q0 = blockIdx.x * 64 + w * 16;

    __shared__ __align__(16) __bf16 Ks[8 * 128 * 8];
    __shared__ __align__(16) __bf16 Vs[16 * 64 * 8];
    __shared__ __align__(16) __bf16 Ps[4][16 * 16 * 8];

    const __bf16* qb = qp + (size_t)(b * SEQ + q0 + fr) * D_MODEL + h * HEAD_DIM;
    const bf16x8 qf0 = *(const bf16x8*)(qb + kq * 8);
    const bf16x8 qf1 = *(const bf16x8*)(qb + 32 + kq * 8);

    const __bf16* kb = kp + (size_t)(b * SEQ) * D_MODEL + h * HEAD_DIM;
    const __bf16* vb = vt + (size_t)bh * HEAD_DIM * SEQ;

    f32x4 acc_o[4];
    #pragma unroll
    for (int dj = 0; dj < 4; ++dj) acc_o[dj] = (f32x4){0.f, 0.f, 0.f, 0.f};
    float m_run[4], l_run[4];
    #pragma unroll
    for (int e = 0; e < 4; ++e) { m_run[e] = -1e30f; l_run[e] = 0.f; }

    for (int kv0 = 0; kv0 < SEQ; kv0 += 128) {
        __syncthreads();
        #pragma unroll
        for (int c = 0; c < 4; ++c) {
            const int s = c * 256 + tid;
            gload16(kb + (size_t)(kv0 + (s & 127)) * D_MODEL + (s >> 7) * 8,
                    &Ks[(size_t)(c * 256 + w * 64) * 8]);
        }
        #pragma unroll
        for (int c = 0; c < 4; ++c) {
            const int s = c * 256 + tid;
            gload16(vb + (size_t)(s & 63) * SEQ + kv0 + (s >> 6) * 8,
                    &Vs[(size_t)(c * 256 + w * 64) * 8]);
        }
        __syncthreads();

        f32x4 sacc[8];
        #pragma unroll
        for (int j = 0; j < 8; ++j) {
            const bf16x8 kf0 = *(const bf16x8*)&Ks[((0 * 4 + kq) * 128 + j * 16 + fr) * 8];
            const bf16x8 kf1 = *(const bf16x8*)&Ks[((1 * 4 + kq) * 128 + j * 16 + fr) * 8];
            sacc[j] = __builtin_amdgcn_mfma_f32_16x16x32_bf16(
                qf0, kf0, (f32x4){0.f, 0.f, 0.f, 0.f}, 0, 0, 0);
            sacc[j] = __builtin_amdgcn_mfma_f32_16x16x32_bf16(qf1, kf1, sacc[j], 0, 0, 0);
        }

        #pragma unroll
        for (int e = 0; e < 4; ++e) {
            float mx = sacc[0][e];
            #pragma unroll
            for (int j = 1; j < 8; ++j) mx = fmaxf(mx, sacc[j][e]);
            mx *= 0.125f;
            #pragma unroll
            for (int off = 1; off < 16; off <<= 1)
                mx = fmaxf(mx, __shfl_xor(mx, off));
            const float m_new = fmaxf(m_run[e], mx);
            const float corr = __expf(m_run[e] - m_new);
            float sum = 0.f;
            #pragma unroll
            for (int j = 0; j < 8; ++j) {
                const float p = __expf(sacc[j][e] * 0.125f - m_new);
                sum += p;
                Ps[w][((j * 2 + (fr >> 3)) * 16 + kq * 4 + e) * 8 + (fr & 7)] = (__bf16)p;
            }
            #pragma unroll
            for (int off = 1; off < 16; off <<= 1)
                sum += __shfl_xor(sum, off);
            l_run[e] = l_run[e] * corr + sum;
            m_run[e] = m_new;
            #pragma unroll
            for (int dj = 0; dj < 4; ++dj) acc_o[dj][e] *= corr;
        }

        #pragma unroll
        for (int m = 0; m < 4; ++m) {
            const bf16x8 pf = *(const bf16x8*)&Ps[w][((m * 4 + kq) * 16 + fr) * 8];
            #pragma unroll
            for (int dj = 0; dj < 4; ++dj) {
                const bf16x8 vf = *(const bf16x8*)&Vs[((m * 4 + kq) * 64 + dj * 16 + fr) * 8];
                acc_o[dj] = __builtin_amdgcn_mfma_f32_16x16x32_bf16(pf, vf, acc_o[dj], 0, 0, 0);
            }
        }
    }

    #pragma unroll
    for (int e = 0; e < 4; ++e) {
        const float inv = 1.0f / l_run[e];
        const size_t rb = (size_t)(b * SEQ + q0 + kq * 4 + e) * D_MODEL + h * HEAD_DIM;
        #pragma unroll
        for (int dj = 0; dj < 4; ++dj)
            o[rb + dj * 16 + fr] = (__bf16)(acc_o[dj][e] * inv);
    }
}

extern "C" void kernel_launch(void* const* d_in, const int* in_sizes, int n_in,
                              void* d_out, int out_size, void* d_ws, size_t ws_size,
                              hipStream_t stream)
{
    const float* x    = (const float*)d_in[0];
    const float* ln1w = (const float*)d_in[1];
    const float* ln1b = (const float*)d_in[2];
    const float* qkvw = (const float*)d_in[3];
    const float* qkvb = (const float*)d_in[4];
    const float* inw  = (const float*)d_in[5];
    const float* inb  = (const float*)d_in[6];
    const float* outw = (const float*)d_in[7];
    const float* outb = (const float*)d_in[8];
    const float* ln2w = (const float*)d_in[9];
    const float* ln2b = (const float*)d_in[10];
    const float* w1   = (const float*)d_in[11];
    const float* b1   = (const float*)d_in[12];
    const float* w2   = (const float*)d_in[13];
    const float* b2   = (const float*)d_in[14];
    float* xo = (float*)d_out;   // running residual stream (fp32)

    // ---- workspace layout (bf16 elements) ----
    // per-layer weights: Wct[3][1024][1024] | OUTt[1024][1024] | W1t[4096][1024] | W2t[1024][4096]
    const size_t OFF_WCT = 0;
    const size_t OFF_OUT = 3145728;
    const size_t OFF_W1  = 4194304;
    const size_t OFF_W2  = 8388608;
    const size_t L_WT    = 12582912;

    __bf16* WT   = (__bf16*)d_ws;                     // 2 x L_WT
    __bf16* QKVb = WT + 2 * L_WT;                     // scratch [1024][3072]
    __bf16* INt  = QKVb + 3145728;                    // scratch [3072][1024]
    __bf16* X8   = INt + 3145728;                     // [4096][1024]
    __bf16* U_   = X8 + 4194304;                      // [4096][4096] mlp-mid
    __bf16* QKV3 = U_ + 16777216;                     // [3][4096][1024] qp,kp,vp
    __bf16* VT   = QKV3 + 12582912;                   // [32][64][2048]
    float*  BC   = (float*)(VT + 4194304);            // [2][3072] combined bias

    hipMemcpyAsync(xo, x, (size_t)TOK * D_MODEL * sizeof(float),
                   hipMemcpyDeviceToDevice, stream);

    const dim3 blk(256);
    // ---- per-layer weight prep ----
    for (int i = 0; i < 2; ++i) {
        __bf16* wl = WT + i * L_WT;
        const float* l_qkvw = qkvw + (size_t)i * D_MODEL * 3 * D_MODEL;
        const float* l_inw  = inw  + (size_t)i * D_MODEL * 3 * D_MODEL;
        // QKVb = bf16(qkv_w) [1024x3072]; INt = bf16(in_w^T) [3072x1024]
        conv_kernel<<<1536, blk, 0, stream>>>(l_qkvw, QKVb, 393216);
        tconv_kernel<<<dim3(96, 32), blk, 0, stream>>>(l_inw, INt, D_MODEL, 3 * D_MODEL);
        // Wct[p][n][k] = sum_j in_w[j, pD+n] * qkv_w[k, pD+j]
        mgemm_z<0, __bf16><<<dim3(8, 8, 3), blk, 0, stream>>>(
            INt, D_MODEL, 1048576, QKVb, 3 * D_MODEL, D_MODEL,
            nullptr, 0, wl + OFF_WCT, D_MODEL, 1048576, D_MODEL);
        // bc[p] = in_b[p] + qkv_b[p] @ in_w[:, p]
        bcomb_kernel<<<12, blk, 0, stream>>>(
            qkvb + (size_t)i * 3 * D_MODEL, l_inw, inb + (size_t)i * 3 * D_MODEL,
            BC + (size_t)i * 3 * D_MODEL);
        tconv_kernel<<<dim3(32, 32), blk, 0, stream>>>(
            outw + (size_t)i * D_MODEL * D_MODEL, wl + OFF_OUT, D_MODEL, D_MODEL);
        tconv_kernel<<<dim3(128, 32), blk, 0, stream>>>(
            w1 + (size_t)i * D_MODEL * MLP_DIM, wl + OFF_W1, D_MODEL, MLP_DIM);
        tconv_kernel<<<dim3(32, 128), blk, 0, stream>>>(
            w2 + (size_t)i * MLP_DIM * D_MODEL, wl + OFF_W2, MLP_DIM, D_MODEL);
    }

    // ---- layers ----
    for (int i = 0; i < 2; ++i) {
        __bf16* wl = WT + i * L_WT;
        const float* l_outb = outb + (size_t)i * D_MODEL;
        const float* l_b1   = b1   + (size_t)i * MLP_DIM;
        const float* l_b2   = b2   + (size_t)i * D_MODEL;

        // h = LN1(x) -> X8
        ln_kernel<<<TOK, blk, 0, stream>>>(xo, ln1w + i * D_MODEL, ln1b + i * D_MODEL, X8);
        // qp/kp/vp = h @ Wct[p]^T + bc[p]  (z-batched, 768 blocks)
        mgemm_z<F_BIAS, __bf16><<<dim3(8, 32, 3), blk, 0, stream>>>(
            X8, D_MODEL, 0, wl + OFF_WCT, D_MODEL, 1048576,
            BC + (size_t)i * 3 * D_MODEL, D_MODEL,
            QKV3, D_MODEL, (long long)TOK * D_MODEL, D_MODEL);
        // VT = transpose(vp)
        tv_kernel<<<dim3(SEQ / 64, BATCH * NHEADS), blk, 0, stream>>>(
            QKV3 + (size_t)2 * TOK * D_MODEL, VT);
        // o = flashattn -> X8
        attn2_kernel<<<dim3(SEQ / 64, BATCH * NHEADS), blk, 0, stream>>>(
            QKV3, QKV3 + (size_t)TOK * D_MODEL, VT, X8);
        // x += o @ out_w + b   (split-K x2, atomic)
        mgemm_splitk<<<dim3(8, 32, 2), blk, 0, stream>>>(
            X8, D_MODEL, wl + OFF_OUT, D_MODEL, l_outb, xo, D_MODEL, 512);
        // h2 = LN2(x) -> X8
        ln_kernel<<<TOK, blk, 0, stream>>>(xo, ln2w + i * D_MODEL, ln2b + i * D_MODEL, X8);
        // m = gelu(h2 @ w1 + b1) -> U_
        mgemm_z<F_BIAS | F_GELU, __bf16><<<dim3(32, 32, 1), blk, 0, stream>>>(
            X8, D_MODEL, 0, wl + OFF_W1, D_MODEL, 0, l_b1, 0, U_, MLP_DIM, 0, D_MODEL);
        // x += m @ w2 + b2   (split-K x4, atomic)
        mgemm_splitk<<<dim3(8, 32, 4), blk, 0, stream>>>(
            U_, MLP_DIM, wl + OFF_W2, MLP_DIM, l_b2, xo, D_MODEL, 1024);
    }
}

// Round 5
// 895.943 us; speedup vs baseline: 8.6993x; 1.2508x over previous
//
#include <hip/hip_runtime.h>
#include <math.h>

#define D_MODEL 1024
#define NHEADS 16
#define HEAD_DIM 64
#define SEQ 2048
#define BATCH 2
#define TOK (BATCH*SEQ)     // 4096 tokens
#define MLP_DIM 4096

#define F_BIAS  1
#define F_GELU  2
#define F_RESID 4

typedef __attribute__((ext_vector_type(8))) __bf16 bf16x8;
typedef __attribute__((ext_vector_type(4))) __bf16 bf16x4;
typedef __attribute__((ext_vector_type(4))) float f32x4;

__device__ __forceinline__ void gload16(const void* g, void* l) {
    __builtin_amdgcn_global_load_lds(
        (const __attribute__((address_space(1))) void*)g,
        (__attribute__((address_space(3))) void*)l, 16, 0, 0);
}

// ---------------- flat fp32 -> bf16 convert ----------------
__global__ __launch_bounds__(256)
void conv_kernel(const float* __restrict__ in, __bf16* __restrict__ out, int n8)
{
    const int idx = blockIdx.x * 256 + threadIdx.x;
    if (idx >= n8) return;
    const float4 a = *(const float4*)(in + idx * 8);
    const float4 b = *(const float4*)(in + idx * 8 + 4);
    bf16x8 o;
    o[0] = (__bf16)a.x; o[1] = (__bf16)a.y; o[2] = (__bf16)a.z; o[3] = (__bf16)a.w;
    o[4] = (__bf16)b.x; o[5] = (__bf16)b.y; o[6] = (__bf16)b.z; o[7] = (__bf16)b.w;
    *(bf16x8*)(out + idx * 8) = o;
}

// ---------------- weight transpose + fp32->bf16: in[R][C] -> out[C][R] ----------------
__global__ __launch_bounds__(256)
void tconv_kernel(const float* __restrict__ in, __bf16* __restrict__ out, int R, int C)
{
    __shared__ float tile[32][33];
    const int bx = blockIdx.x;          // C/32
    const int by = blockIdx.y;          // R/32
    const int tx = threadIdx.x & 31;
    const int ty = threadIdx.x >> 5;    // 0..7
    #pragma unroll
    for (int i = 0; i < 4; ++i)
        tile[ty * 4 + i][tx] = in[(size_t)(by * 32 + ty * 4 + i) * C + bx * 32 + tx];
    __syncthreads();
    #pragma unroll
    for (int i = 0; i < 4; ++i)
        out[(size_t)(bx * 32 + ty * 4 + i) * R + by * 32 + tx] = (__bf16)tile[tx][ty * 4 + i];
}

// ---------------- combined bias: bc[p][n] = in_b[p*D+n] + sum_k qkv_b[p*D+k]*in_w[k][p*D+n]
__global__ __launch_bounds__(256)
void bcomb_kernel(const float* __restrict__ qkv_b, const float* __restrict__ in_w,
                  const float* __restrict__ in_b, float* __restrict__ bc)
{
    const int t = blockIdx.x * 256 + threadIdx.x;   // 0..3071
    const int p = t >> 10, n = t & 1023;
    float s = in_b[t];
    #pragma unroll 16
    for (int k = 0; k < D_MODEL; ++k)
        s = fmaf(qkv_b[p * D_MODEL + k], in_w[(size_t)k * 3 * D_MODEL + p * D_MODEL + n], s);
    bc[t] = s;
}

// ---------------- V transpose: v[b*S+s][h*64+d](bf16) -> vt[bh][d][s](bf16) ----------
__global__ __launch_bounds__(256)
void tv_kernel(const __bf16* __restrict__ v, __bf16* __restrict__ vt)
{
    __shared__ __bf16 t[64][72];
    const int bh = blockIdx.y, b = bh >> 4, h = bh & 15;
    const int s0 = blockIdx.x * 64;
    const int r = threadIdx.x >> 3;         // 0..31
    const int c = (threadIdx.x & 7) * 8;    // 0..56
    #pragma unroll
    for (int rr = 0; rr < 64; rr += 32) {
        bf16x8 x = *(const bf16x8*)&v[(size_t)(b * SEQ + s0 + r + rr) * D_MODEL + h * 64 + c];
        #pragma unroll
        for (int k = 0; k < 8; ++k) t[r + rr][c + k] = x[k];
    }
    __syncthreads();
    #pragma unroll
    for (int rr = 0; rr < 64; rr += 32) {
        bf16x8 y;
        #pragma unroll
        for (int k = 0; k < 8; ++k) y[k] = t[c + k][r + rr];
        *(bf16x8*)&vt[((size_t)bh * 64 + r + rr) * SEQ + s0 + c] = y;
    }
}

// ---------------- LayerNorm: fp32 in, bf16 out ----------------
__device__ __forceinline__ void ln_body(float4 v, const float* w, const float* b,
                                        __bf16* out, int row, int t)
{
    float s  = v.x + v.y + v.z + v.w;
    float ss = v.x*v.x + v.y*v.y + v.z*v.z + v.w*v.w;
    #pragma unroll
    for (int off = 32; off > 0; off >>= 1) {
        s  += __shfl_down(s, off);
        ss += __shfl_down(ss, off);
    }
    __shared__ float red[8];
    const int wid = t >> 6, lane = t & 63;
    if (lane == 0) { red[wid] = s; red[4 + wid] = ss; }
    __syncthreads();
    const float st  = red[0] + red[1] + red[2] + red[3];
    const float sst = red[4] + red[5] + red[6] + red[7];
    const float mu  = st * (1.0f / D_MODEL);
    const float var = sst * (1.0f / D_MODEL) - mu * mu;
    const float rs  = rsqrtf(var + 1e-5f);
    const float4 wv = *(const float4*)(w + t * 4);
    const float4 bv = *(const float4*)(b + t * 4);
    bf16x4 o;
    o[0] = (__bf16)((v.x - mu) * rs * wv.x + bv.x);
    o[1] = (__bf16)((v.y - mu) * rs * wv.y + bv.y);
    o[2] = (__bf16)((v.z - mu) * rs * wv.z + bv.z);
    o[3] = (__bf16)((v.w - mu) * rs * wv.w + bv.w);
    *(bf16x4*)(out + (size_t)row * D_MODEL + t * 4) = o;
}

__global__ __launch_bounds__(256)
void ln_kernel(const float* __restrict__ x, const float* __restrict__ w,
               const float* __restrict__ b, __bf16* __restrict__ out)
{
    const int row = blockIdx.x, t = threadIdx.x;
    float4 v = *(const float4*)(x + (size_t)row * D_MODEL + t * 4);
    ln_body(v, w, b, out, row, t);
}

// x += p0 + p1 (write back), then LN -> out
__global__ __launch_bounds__(256)
void ln_add_kernel(float* __restrict__ x, const float* __restrict__ p0,
                   const float* __restrict__ p1, const float* __restrict__ w,
                   const float* __restrict__ b, __bf16* __restrict__ out)
{
    const int row = blockIdx.x, t = threadIdx.x;
    const size_t idx = (size_t)row * D_MODEL + t * 4;
    float4 v  = *(const float4*)(x + idx);
    float4 a0 = *(const float4*)(p0 + idx);
    float4 a1 = *(const float4*)(p1 + idx);
    v.x += a0.x + a1.x; v.y += a0.y + a1.y;
    v.z += a0.z + a1.z; v.w += a0.w + a1.w;
    *(float4*)(x + idx) = v;
    ln_body(v, w, b, out, row, t);
}

// x += p0 + p1 (final)
__global__ __launch_bounds__(256)
void add2_kernel(float* __restrict__ x, const float* __restrict__ p0,
                 const float* __restrict__ p1)
{
    const size_t idx = ((size_t)blockIdx.x * 256 + threadIdx.x) * 4;
    float4 v  = *(const float4*)(x + idx);
    float4 a0 = *(const float4*)(p0 + idx);
    float4 a1 = *(const float4*)(p1 + idx);
    v.x += a0.x + a1.x; v.y += a0.y + a1.y;
    v.z += a0.z + a1.z; v.w += a0.w + a1.w;
    *(float4*)(x + idx) = v;
}

// ---------------- MFMA GEMM core: 128x128 tile, BK=32, double-buffered 2-phase ------
// As/Bs are [2][4096] element buffers. One barrier per K-step; next tile's
// global_load_lds issued before current tile's compute (T3-minimal pipeline).
__device__ __forceinline__ void mgemm_acc(
    const __bf16* __restrict__ A, int lda,
    const __bf16* __restrict__ Bt, int ldb, int K,
    __bf16* As, __bf16* Bs, f32x4 (&acc)[4][4])
{
    const int tid  = threadIdx.x;
    const int lane = tid & 63;
    const int w    = tid >> 6;
    const int wm   = w >> 1, wn = w & 1;
    const int bm = blockIdx.y, bn = blockIdx.x;

    const int s1 = 256 + tid;
    const int kc0 = tid >> 7, r0 = tid & 127;
    const int kc1 = s1  >> 7, r1 = s1 & 127;

    const __bf16* a0p = A  + (size_t)(bm * 128 + r0) * lda + kc0 * 8;
    const __bf16* a1p = A  + (size_t)(bm * 128 + r1) * lda + kc1 * 8;
    const __bf16* b0p = Bt + (size_t)(bn * 128 + r0) * ldb + kc0 * 8;
    const __bf16* b1p = Bt + (size_t)(bn * 128 + r1) * ldb + kc1 * 8;

    const int sl0 = (0 * 256 + w * 64) * 8;
    const int sl1 = (1 * 256 + w * 64) * 8;

    const int kq = lane >> 4;
    const int fr = lane & 15;
    const int aidx = (kq * 128 + wm * 64 + fr) * 8;
    const int bidx = (kq * 128 + wn * 64 + fr) * 8;

#define MG_STAGE(buf, k0) do { \
        gload16(a0p + (k0), As + (buf) * 4096 + sl0); \
        gload16(a1p + (k0), As + (buf) * 4096 + sl1); \
        gload16(b0p + (k0), Bs + (buf) * 4096 + sl0); \
        gload16(b1p + (k0), Bs + (buf) * 4096 + sl1); \
    } while (0)

    MG_STAGE(0, 0);
    __syncthreads();     // drains vmcnt -> buf0 ready
    int cur = 0;
    for (int k0 = 0; k0 < K; k0 += 32) {
        if (k0 + 32 < K) MG_STAGE(cur ^ 1, k0 + 32);   // prefetch in flight over MFMA
        const __bf16* as = As + cur * 4096;
        const __bf16* bs = Bs + cur * 4096;
        bf16x8 af[4], bfr[4];
        #pragma unroll
        for (int i = 0; i < 4; ++i) {
            af[i]  = *(const bf16x8*)&as[aidx + i * 128];
            bfr[i] = *(const bf16x8*)&bs[bidx + i * 128];
        }
        #pragma unroll
        for (int i = 0; i < 4; ++i)
            #pragma unroll
            for (int j = 0; j < 4; ++j)
                acc[i][j] = __builtin_amdgcn_mfma_f32_16x16x32_bf16(
                    af[i], bfr[j], acc[i][j], 0, 0, 0);
        __syncthreads();   // all reads of buf cur done; prefetch drained
        cur ^= 1;
    }
#undef MG_STAGE
}

// ---------------- generic z-batched GEMM: per-z operand strides ----------------
template<int FLAGS, typename CT>
__global__ __launch_bounds__(256)
void mgemm_z(const __bf16* __restrict__ A, int lda, long long sAz,
             const __bf16* __restrict__ Bt, int ldb, long long sBz,
             const float* __restrict__ bias, long long sbz,
             CT* __restrict__ C, int ldc, long long sCz, int K)
{
    __shared__ __bf16 As[2 * 4096];
    __shared__ __bf16 Bs[2 * 4096];
    const int z = blockIdx.z;
    A  += (size_t)z * sAz;
    Bt += (size_t)z * sBz;
    C  += (size_t)z * sCz;
    if (FLAGS & F_BIAS) bias += (size_t)z * sbz;

    f32x4 acc[4][4];
    #pragma unroll
    for (int i = 0; i < 4; ++i)
        #pragma unroll
        for (int j = 0; j < 4; ++j)
            acc[i][j] = (f32x4){0.f, 0.f, 0.f, 0.f};

    mgemm_acc(A, lda, Bt, ldb, K, As, Bs, acc);

    const int lane = threadIdx.x & 63;
    const int w    = threadIdx.x >> 6;
    const int row0 = blockIdx.y * 128 + (w >> 1) * 64 + (lane >> 4) * 4;
    const int col0 = blockIdx.x * 128 + (w & 1) * 64 + (lane & 15);
    #pragma unroll
    for (int i = 0; i < 4; ++i) {
        #pragma unroll
        for (int j = 0; j < 4; ++j) {
            const int col = col0 + j * 16;
            float bb = (FLAGS & F_BIAS) ? bias[col] : 0.0f;
            #pragma unroll
            for (int e = 0; e < 4; ++e) {
                const int row = row0 + i * 16 + e;
                float val = acc[i][j][e] + bb;
                if (FLAGS & F_GELU)
                    val = 0.5f * val * (1.0f + erff(val * 0.70710678118654752f));
                if (FLAGS & F_RESID)
                    val += (float)C[(size_t)row * ldc + col];
                C[(size_t)row * ldc + col] = (CT)val;
            }
        }
    }
}

// ---------------- split-K GEMM: z = k-slice, plain fp32 partial stores ----------------
__global__ __launch_bounds__(256)
void mgemm_splitk(const __bf16* __restrict__ A, int lda,
                  const __bf16* __restrict__ Bt, int ldb,
                  const float* __restrict__ bias,
                  float* __restrict__ P, int ldc, int KS)
{
    __shared__ __bf16 As[2 * 4096];
    __shared__ __bf16 Bs[2 * 4096];
    const int z = blockIdx.z;
    A  += (size_t)z * KS;
    Bt += (size_t)z * KS;
    float* C = P + (size_t)z * TOK * D_MODEL;

    f32x4 acc[4][4];
    #pragma unroll
    for (int i = 0; i < 4; ++i)
        #pragma unroll
        for (int j = 0; j < 4; ++j)
            acc[i][j] = (f32x4){0.f, 0.f, 0.f, 0.f};

    mgemm_acc(A, lda, Bt, ldb, KS, As, Bs, acc);

    const int lane = threadIdx.x & 63;
    const int w    = threadIdx.x >> 6;
    const int row0 = blockIdx.y * 128 + (w >> 1) * 64 + (lane >> 4) * 4;
    const int col0 = blockIdx.x * 128 + (w & 1) * 64 + (lane & 15);
    #pragma unroll
    for (int i = 0; i < 4; ++i) {
        #pragma unroll
        for (int j = 0; j < 4; ++j) {
            const int col = col0 + j * 16;
            const float bb = (z == 0) ? bias[col] : 0.0f;
            #pragma unroll
            for (int e = 0; e < 4; ++e) {
                const int row = row0 + i * 16 + e;
                C[(size_t)row * ldc + col] = acc[i][j][e] + bb;
            }
        }
    }
}

// ---------------- MFMA flash attention, swapped-operand (S^T = K Q^T) ----------------
// grid (S/64, B*H), 4 waves; wave w owns q rows [q0, q0+16), q = lane&15.
// Per 64-kv tile: S^T via mfma(K-frag, Q-frag) -> lane holds 16 kv-values of
// ONE q-column; softmax scalar m/l per lane + 2 shfl_xor; P^T packed b64 to
// LDS; PV = mfma(V^T-frag, P^T-frag) accumulates O^T (d rows, q cols).
__global__ __launch_bounds__(256)
void attn3_kernel(const __bf16* __restrict__ qp, const __bf16* __restrict__ kp,
                  const __bf16* __restrict__ vt, __bf16* __restrict__ o)
{
    const int bh = blockIdx.y;
    const int b = bh >> 4, h = bh & 15;
    const int tid = threadIdx.x;
    const int lane = tid & 63;
    const int w = tid >> 6;
    const int g = lane >> 4;        // k-chunk group 0..3
    const int fr = lane & 15;       // q within wave tile
    const int q0 = blockIdx.x * 64 + w * 16;

    __shared__ __align__(16) __bf16 Ks[8 * 64 * 8];    // [kc=d/8][kv][8]  8KB
    __shared__ __align__(16) __bf16 Vs[8 * 64 * 8];    // [kc=kv/8][d][8]  8KB
    __shared__ __align__(16) __bf16 Ps[4][16 * 72];    // per-wave P^T [q][kv(+pad)]

    // Q as B-frag: col=q=fr, k=d=g*8+e (two 32-wide chunks)
    const __bf16* qb = qp + (size_t)(b * SEQ + q0 + fr) * D_MODEL + h * HEAD_DIM;
    const bf16x8 qf0 = *(const bf16x8*)(qb + g * 8);
    const bf16x8 qf1 = *(const bf16x8*)(qb + 32 + g * 8);

    const __bf16* kb = kp + (size_t)(b * SEQ) * D_MODEL + h * HEAD_DIM;
    const __bf16* vb = vt + (size_t)bh * HEAD_DIM * SEQ;

    f32x4 acc_o[4];   // acc_o[dj][e] = O^T[d=16dj+4g+e][q0+fr]
    #pragma unroll
    for (int dj = 0; dj < 4; ++dj) acc_o[dj] = (f32x4){0.f, 0.f, 0.f, 0.f};
    float m_run = -1e30f, l_run = 0.0f;

    for (int kv0 = 0; kv0 < SEQ; kv0 += 64) {
        __syncthreads();   // previous tile fully consumed
        #pragma unroll
        for (int c = 0; c < 2; ++c) {       // K: slot s -> kc=s>>6, kv=s&63
            const int s = c * 256 + tid;
            gload16(kb + (size_t)(kv0 + (s & 63)) * D_MODEL + (s >> 6) * 8,
                    &Ks[(c * 256 + w * 64) * 8]);
        }
        #pragma unroll
        for (int c = 0; c < 2; ++c) {       // V^T: slot s -> kc=s>>6, d=s&63
            const int s = c * 256 + tid;
            gload16(vb + (size_t)(s & 63) * SEQ + kv0 + (s >> 6) * 8,
                    &Vs[(c * 256 + w * 64) * 8]);
        }
        __syncthreads();   // tiles ready

        // ---- S^T tiles t=0..3 (kv 16t..16t+15): A=K rows=kv k=d; B=Q ----
        f32x4 sacc[4];
        __builtin_amdgcn_s_setprio(1);
        #pragma unroll
        for (int t = 0; t < 4; ++t) {
            const bf16x8 kf0 = *(const bf16x8*)&Ks[((g    ) * 64 + t * 16 + fr) * 8];
            const bf16x8 kf1 = *(const bf16x8*)&Ks[((4 + g) * 64 + t * 16 + fr) * 8];
            sacc[t] = __builtin_amdgcn_mfma_f32_16x16x32_bf16(
                kf0, qf0, (f32x4){0.f, 0.f, 0.f, 0.f}, 0, 0, 0);
            sacc[t] = __builtin_amdgcn_mfma_f32_16x16x32_bf16(kf1, qf1, sacc[t], 0, 0, 0);
        }
        __builtin_amdgcn_s_setprio(0);

        // ---- online softmax for q=fr over this tile's 64 kv ----
        float mx = -1e30f;
        #pragma unroll
        for (int t = 0; t < 4; ++t)
            #pragma unroll
            for (int e = 0; e < 4; ++e) mx = fmaxf(mx, sacc[t][e]);
        mx *= 0.125f;
        mx = fmaxf(mx, __shfl_xor(mx, 16));
        mx = fmaxf(mx, __shfl_xor(mx, 32));
        const float m_new = fmaxf(m_run, mx);
        const float corr = __expf(m_run - m_new);
        float lsum = 0.0f;
        #pragma unroll
        for (int t = 0; t < 4; ++t) {
            bf16x4 pv;
            #pragma unroll
            for (int e = 0; e < 4; ++e) {
                const float p = __expf(sacc[t][e] * 0.125f - m_new);
                lsum += p;
                pv[e] = (__bf16)p;
            }
            *(bf16x4*)&Ps[w][fr * 72 + t * 16 + g * 4] = pv;   // P^T[kv=16t+4g..][q=fr]
        }
        lsum += __shfl_xor(lsum, 16);
        lsum += __shfl_xor(lsum, 32);
        l_run = l_run * corr + lsum;
        m_run = m_new;
        #pragma unroll
        for (int dj = 0; dj < 4; ++dj)
            #pragma unroll
            for (int e = 0; e < 4; ++e) acc_o[dj][e] *= corr;

        // ---- O^T += V^T @ P^T  (same-wave LDS dep; compiler inserts lgkmcnt) ----
        __builtin_amdgcn_s_setprio(1);
        #pragma unroll
        for (int c = 0; c < 2; ++c) {
            const bf16x8 pf = *(const bf16x8*)&Ps[w][fr * 72 + c * 32 + g * 8];
            #pragma unroll
            for (int dj = 0; dj < 4; ++dj) {
                const bf16x8 vf = *(const bf16x8*)&Vs[((c * 4 + g) * 64 + dj * 16 + fr) * 8];
                acc_o[dj] = __builtin_amdgcn_mfma_f32_16x16x32_bf16(vf, pf, acc_o[dj], 0, 0, 0);
            }
        }
        __builtin_amdgcn_s_setprio(0);
    }

    // epilogue: lane holds q=q0+fr, d = 16dj+4g+e
    const float inv = 1.0f / l_run;
    __bf16* orow = o + (size_t)(b * SEQ + q0 + fr) * D_MODEL + h * HEAD_DIM;
    #pragma unroll
    for (int dj = 0; dj < 4; ++dj) {
        bf16x4 t;
        #pragma unroll
        for (int e = 0; e < 4; ++e) t[e] = (__bf16)(acc_o[dj][e] * inv);
        *(bf16x4*)&orow[dj * 16 + g * 4] = t;
    }
}

extern "C" void kernel_launch(void* const* d_in, const int* in_sizes, int n_in,
                              void* d_out, int out_size, void* d_ws, size_t ws_size,
                              hipStream_t stream)
{
    const float* x    = (const float*)d_in[0];
    const float* ln1w = (const float*)d_in[1];
    const float* ln1b = (const float*)d_in[2];
    const float* qkvw = (const float*)d_in[3];
    const float* qkvb = (const float*)d_in[4];
    const float* inw  = (const float*)d_in[5];
    const float* inb  = (const float*)d_in[6];
    const float* outw = (const float*)d_in[7];
    const float* outb = (const float*)d_in[8];
    const float* ln2w = (const float*)d_in[9];
    const float* ln2b = (const float*)d_in[10];
    const float* w1   = (const float*)d_in[11];
    const float* b1   = (const float*)d_in[12];
    const float* w2   = (const float*)d_in[13];
    const float* b2   = (const float*)d_in[14];
    float* xo = (float*)d_out;   // running residual stream (fp32)

    // ---- workspace layout (bf16 elements) ----
    const size_t OFF_WCT = 0;
    const size_t OFF_OUT = 3145728;
    const size_t OFF_W1  = 4194304;
    const size_t OFF_W2  = 8388608;
    const size_t L_WT    = 12582912;

    __bf16* WT   = (__bf16*)d_ws;                     // 2 x L_WT
    __bf16* QKVb = WT + 2 * L_WT;                     // scratch [1024][3072]
    __bf16* INt  = QKVb + 3145728;                    // scratch [3072][1024]
    __bf16* X8   = INt + 3145728;                     // [4096][1024]
    __bf16* U_   = X8 + 4194304;                      // [4096][4096] mlp-mid
    __bf16* QKV3 = U_ + 16777216;                     // [3][4096][1024] qp,kp,vp
    __bf16* VT   = QKV3 + 12582912;                   // [32][64][2048]
    float*  BC   = (float*)(VT + 4194304);            // [2][3072] combined bias
    // split-K partials alias QKV3+VT (exactly 2 x 4096x1024 fp32); lifetimes disjoint
    float*  P_   = (float*)QKV3;

    hipMemcpyAsync(xo, x, (size_t)TOK * D_MODEL * sizeof(float),
                   hipMemcpyDeviceToDevice, stream);

    const dim3 blk(256);
    // ---- per-layer weight prep ----
    for (int i = 0; i < 2; ++i) {
        __bf16* wl = WT + i * L_WT;
        const float* l_qkvw = qkvw + (size_t)i * D_MODEL * 3 * D_MODEL;
        const float* l_inw  = inw  + (size_t)i * D_MODEL * 3 * D_MODEL;
        conv_kernel<<<1536, blk, 0, stream>>>(l_qkvw, QKVb, 393216);
        tconv_kernel<<<dim3(96, 32), blk, 0, stream>>>(l_inw, INt, D_MODEL, 3 * D_MODEL);
        // Wct[p] = (in_w_p)^T (qkv_w_p)^T  -> [3][1024][1024]
        mgemm_z<0, __bf16><<<dim3(8, 8, 3), blk, 0, stream>>>(
            INt, D_MODEL, 1048576, QKVb, 3 * D_MODEL, D_MODEL,
            nullptr, 0, wl + OFF_WCT, D_MODEL, 1048576, D_MODEL);
        bcomb_kernel<<<12, blk, 0, stream>>>(
            qkvb + (size_t)i * 3 * D_MODEL, l_inw, inb + (size_t)i * 3 * D_MODEL,
            BC + (size_t)i * 3 * D_MODEL);
        tconv_kernel<<<dim3(32, 32), blk, 0, stream>>>(
            outw + (size_t)i * D_MODEL * D_MODEL, wl + OFF_OUT, D_MODEL, D_MODEL);
        tconv_kernel<<<dim3(128, 32), blk, 0, stream>>>(
            w1 + (size_t)i * D_MODEL * MLP_DIM, wl + OFF_W1, D_MODEL, MLP_DIM);
        tconv_kernel<<<dim3(32, 128), blk, 0, stream>>>(
            w2 + (size_t)i * MLP_DIM * D_MODEL, wl + OFF_W2, MLP_DIM, D_MODEL);
    }

    // ---- layers ----
    for (int i = 0; i < 2; ++i) {
        __bf16* wl = WT + i * L_WT;
        const float* l_outb = outb + (size_t)i * D_MODEL;
        const float* l_b1   = b1   + (size_t)i * MLP_DIM;
        const float* l_b2   = b2   + (size_t)i * D_MODEL;

        // h = LN1(x) -> X8   (layer 0: plain; layer 1 folded into prev ln_add)
        if (i == 0)
            ln_kernel<<<TOK, blk, 0, stream>>>(xo, ln1w, ln1b, X8);
        // qp/kp/vp = h @ Wct[p]^T + bc[p]  (z-batched, 768 blocks)
        mgemm_z<F_BIAS, __bf16><<<dim3(8, 32, 3), blk, 0, stream>>>(
            X8, D_MODEL, 0, wl + OFF_WCT, D_MODEL, 1048576,
            BC + (size_t)i * 3 * D_MODEL, D_MODEL,
            QKV3, D_MODEL, (long long)TOK * D_MODEL, D_MODEL);
        // VT = transpose(vp)
        tv_kernel<<<dim3(SEQ / 64, BATCH * NHEADS), blk, 0, stream>>>(
            QKV3 + (size_t)2 * TOK * D_MODEL, VT);
        // o = flashattn -> X8
        attn3_kernel<<<dim3(SEQ / 64, BATCH * NHEADS), blk, 0, stream>>>(
            QKV3, QKV3 + (size_t)TOK * D_MODEL, VT, X8);
        // out-proj partials (split-K x2): P_[z] = X8 @ out_w slice (+bias on z0)
        mgemm_splitk<<<dim3(8, 32, 2), blk, 0, stream>>>(
            X8, D_MODEL, wl + OFF_OUT, D_MODEL, l_outb, P_, D_MODEL, 512);
        // x += p0+p1 ; h2 = LN2(x) -> X8
        ln_add_kernel<<<TOK, blk, 0, stream>>>(
            xo, P_, P_ + (size_t)TOK * D_MODEL,
            ln2w + (size_t)i * D_MODEL, ln2b + (size_t)i * D_MODEL, X8);
        // m = gelu(h2 @ w1 + b1) -> U_
        mgemm_z<F_BIAS | F_GELU, __bf16><<<dim3(32, 32, 1), blk, 0, stream>>>(
            X8, D_MODEL, 0, wl + OFF_W1, D_MODEL, 0, l_b1, 0, U_, MLP_DIM, 0, D_MODEL);
        // w2 partials (split-K x2)
        mgemm_splitk<<<dim3(8, 32, 2), blk, 0, stream>>>(
            U_, MLP_DIM, wl + OFF_W2, MLP_DIM, l_b2, P_, D_MODEL, 2048);
        if (i == 0) {
            // x += p0+p1 ; h = LN1_next(x) -> X8
            ln_add_kernel<<<TOK, blk, 0, stream>>>(
                xo, P_, P_ + (size_t)TOK * D_MODEL,
                ln1w + D_MODEL, ln1b + D_MODEL, X8);
        } else {
            add2_kernel<<<TOK * D_MODEL / 1024, blk, 0, stream>>>(
                xo, P_, P_ + (size_t)TOK * D_MODEL);
        }
    }
}